// Round 3
// baseline (3815.081 us; speedup 1.0000x reference)
//
#include <hip/hip_runtime.h>
#include <math.h>

#define SQ 192      // S
#define BB 192      // B
#define DM 512
#define NH 8
#define DH 64
#define NEPS 1e-5f
#define ASCALE 0.125f   // 1/sqrt(64)
#define K3 1536         // 3*DM split-K

typedef __bf16 bf16x8 __attribute__((ext_vector_type(8)));
typedef float f32x4 __attribute__((ext_vector_type(4)));

__device__ __forceinline__ void gload_lds16(const unsigned short* g, unsigned short* l) {
  __builtin_amdgcn_global_load_lds(
      (const __attribute__((address_space(1))) void*)g,
      (__attribute__((address_space(3))) void*)l, 16, 0, 0);
}

// ---------------------------------------------------------------------------
// Fused double LayerNorm: h = LN2(LN1(inp)). One block (128 thr) per row.
// Reads s-major row (s*B+b), writes b-major row (b*S+s)  -> h' in d_out.
// ---------------------------------------------------------------------------
__global__ __launch_bounds__(128) void ln2_kernel(
    const float* __restrict__ inp, const float* __restrict__ g1, const float* __restrict__ b1,
    const float* __restrict__ g2, const float* __restrict__ b2, float* __restrict__ h) {
  const int R = blockIdx.x;              // input row s*B+b
  const int s = R / BB;
  const int b = R % BB;
  const int t = threadIdx.x;
  const float4 v = reinterpret_cast<const float4*>(inp + (size_t)R * DM)[t];
  float sum  = v.x + v.y + v.z + v.w;
  float sum2 = v.x*v.x + v.y*v.y + v.z*v.z + v.w*v.w;
  #pragma unroll
  for (int o = 32; o >= 1; o >>= 1) { sum += __shfl_xor(sum, o); sum2 += __shfl_xor(sum2, o); }
  __shared__ float red[2][2];
  const int wv = t >> 6;
  if ((t & 63) == 0) { red[0][wv] = sum; red[1][wv] = sum2; }
  __syncthreads();
  sum = red[0][0] + red[0][1]; sum2 = red[1][0] + red[1][1];
  float mu = sum * (1.0f / DM);
  float var = sum2 * (1.0f / DM) - mu * mu;
  float rstd = rsqrtf(var + NEPS);
  const float4 G1 = reinterpret_cast<const float4*>(g1)[t];
  const float4 B1 = reinterpret_cast<const float4*>(b1)[t];
  float4 x;
  x.x = (v.x - mu) * rstd * G1.x + B1.x;
  x.y = (v.y - mu) * rstd * G1.y + B1.y;
  x.z = (v.z - mu) * rstd * G1.z + B1.z;
  x.w = (v.w - mu) * rstd * G1.w + B1.w;
  sum  = x.x + x.y + x.z + x.w;
  sum2 = x.x*x.x + x.y*x.y + x.z*x.z + x.w*x.w;
  #pragma unroll
  for (int o = 32; o >= 1; o >>= 1) { sum += __shfl_xor(sum, o); sum2 += __shfl_xor(sum2, o); }
  __syncthreads();
  if ((t & 63) == 0) { red[0][wv] = sum; red[1][wv] = sum2; }
  __syncthreads();
  sum = red[0][0] + red[0][1]; sum2 = red[1][0] + red[1][1];
  mu = sum * (1.0f / DM);
  var = sum2 * (1.0f / DM) - mu * mu;
  rstd = rsqrtf(var + NEPS);
  const float4 G2 = reinterpret_cast<const float4*>(g2)[t];
  const float4 B2 = reinterpret_cast<const float4*>(b2)[t];
  float4 o4;
  o4.x = (x.x - mu) * rstd * G2.x + B2.x;
  o4.y = (x.y - mu) * rstd * G2.y + B2.y;
  o4.z = (x.z - mu) * rstd * G2.z + B2.z;
  o4.w = (x.w - mu) * rstd * G2.w + B2.w;
  reinterpret_cast<float4*>(h + ((size_t)b * SQ + s) * DM)[t] = o4;
}

// ---------------------------------------------------------------------------
__global__ void posemb_kernel(const float* __restrict__ inp, float* __restrict__ pe) {
  const int idx = blockIdx.x * 256 + threadIdx.x;
  if (idx >= BB * DM) return;
  const int b = idx >> 9;
  const int d = idx & 511;
  const float ps = inp[(size_t)b * DM];
  const int i = (d < 256) ? d : (d - 256);
  const float invf = expf(-9.210340371976184f * (float)i * (1.0f / 256.0f));
  const float a = ps * invf;
  pe[idx] = (d < 256) ? sinf(a) : cosf(a);
}

// ---------------------------------------------------------------------------
__global__ __launch_bounds__(256) void rhk_kernel(
    const float* __restrict__ pe, const float* __restrict__ Wr, float* __restrict__ rhk) {
  __shared__ __align__(16) float pr[DM];
  const int j = blockIdx.x;
  const int e = blockIdx.y * 256 + threadIdx.x;
  for (int d = threadIdx.x; d < DM; d += 256) pr[d] = pe[(size_t)j * DM + d];
  __syncthreads();
  const float4* w4 = reinterpret_cast<const float4*>(Wr + (size_t)e * DM);
  const float4* p4 = reinterpret_cast<const float4*>(pr);
  float acc = 0.f;
  #pragma unroll 8
  for (int d4 = 0; d4 < DM / 4; ++d4) {
    const float4 a = p4[d4];
    const float4 w = w4[d4];
    acc += a.x*w.x + a.y*w.y + a.z*w.z + a.w*w.w;
  }
  rhk[(size_t)j * DM + e] = acc;
}

// ---------------------------------------------------------------------------
// fp32 -> split-bf16 conversion. src: nrows x 512 fp32. dst: nrows x 1536 bf16.
// bside=0 (A-side): [hi | lo | hi].  bside=1 (B-side): [hi | hi | lo].
// (A'.B'^T over K'=1536 == Ahi.Bhi + Alo.Bhi + Ahi.Blo ~= fp32 product)
// ---------------------------------------------------------------------------
__global__ __launch_bounds__(256) void conv_split_kernel(
    const float* __restrict__ src, unsigned short* __restrict__ dst,
    int nrows, int bside) {
  const int idx = blockIdx.x * 256 + threadIdx.x;
  if (idx >= nrows * DM) return;
  const int r = idx >> 9;
  const int c = idx & 511;
  const float x = src[idx];
  union { float f; unsigned int u; } cv; cv.f = x;
  const unsigned int u = cv.u;
  const unsigned int hibits = (u + 0x7fffu + ((u >> 16) & 1u)) & 0xffff0000u;
  const unsigned short hi = (unsigned short)(hibits >> 16);
  union { unsigned int u; float f; } hb; hb.u = hibits;
  const float lof = x - hb.f;                       // exact residual
  union { float f; unsigned int u; } lv; lv.f = lof;
  const unsigned int lu = lv.u;
  const unsigned short lo = (unsigned short)((lu + 0x7fffu + ((lu >> 16) & 1u)) >> 16);
  unsigned short* drow = dst + (size_t)r * K3 + c;
  drow[0]    = hi;
  drow[512]  = bside ? hi : lo;
  drow[1024] = bside ? lo : hi;
}

// ---------------------------------------------------------------------------
// bf16 NT MFMA GEMM (m97 structure): C[m][n] = sum_k A[m][k]*B[n][k], fp32 out.
// 128x128 tile, BK=32, 256 thr (4 waves, 2x2 of 64x64), 16x16x32 bf16 MFMA.
// permute: 0 -> C row rr at rr; 1 -> at (rr%SQ)*BB + rr/SQ (chunk-global rows).
// Rows multiple of 128 via grid.y; K % 32 == 0.
// ---------------------------------------------------------------------------
__global__ __launch_bounds__(256) void gemm_mfma(
    const unsigned short* __restrict__ Ab, const unsigned short* __restrict__ Bb,
    float* __restrict__ C, int N, int K, int permute) {
  __shared__ __align__(16) unsigned short As[128 * 32];
  __shared__ __align__(16) unsigned short Bs[128 * 32];
  const int tid = threadIdx.x;
  const int bm = blockIdx.y * 128;
  const int bn = blockIdx.x * 128;
  const int lane = tid & 63;
  const int wv = tid >> 6;
  const int wm = (wv >> 1) << 6;     // wave row offset: 0 / 64
  const int wn = (wv & 1) << 6;      // wave col offset: 0 / 64
  const int fr = lane & 15;          // fragment row (M or N index)
  const int fk = (lane >> 4) << 3;   // fragment k offset (8 bf16 chunk)

  const unsigned short* Arow = Ab + (size_t)(bm + (tid >> 2)) * K + ((tid & 3) << 3);
  const unsigned short* Brow = Bb + (size_t)(bn + (tid >> 2)) * K + ((tid & 3) << 3);
  unsigned short* ldsA0 = As + tid * 8;
  unsigned short* ldsA1 = As + 2048 + tid * 8;
  unsigned short* ldsB0 = Bs + tid * 8;
  unsigned short* ldsB1 = Bs + 2048 + tid * 8;
  const size_t half_off = (size_t)64 * K;

  f32x4 acc[4][4];
  #pragma unroll
  for (int m = 0; m < 4; ++m)
    #pragma unroll
    for (int n = 0; n < 4; ++n) acc[m][n] = (f32x4){0.f, 0.f, 0.f, 0.f};

  for (int k0 = 0; k0 < K; k0 += 32) {
    gload_lds16(Arow + k0, ldsA0);
    gload_lds16(Arow + half_off + k0, ldsA1);
    gload_lds16(Brow + k0, ldsB0);
    gload_lds16(Brow + half_off + k0, ldsB1);
    __syncthreads();   // drains vmcnt before barrier
    bf16x8 af[4], bg[4];
    #pragma unroll
    for (int m = 0; m < 4; ++m)
      af[m] = *reinterpret_cast<const bf16x8*>(&As[(wm + m * 16 + fr) * 32 + fk]);
    #pragma unroll
    for (int n = 0; n < 4; ++n)
      bg[n] = *reinterpret_cast<const bf16x8*>(&Bs[(wn + n * 16 + fr) * 32 + fk]);
    #pragma unroll
    for (int m = 0; m < 4; ++m)
      #pragma unroll
      for (int n = 0; n < 4; ++n)
        acc[m][n] = __builtin_amdgcn_mfma_f32_16x16x32_bf16(af[m], bg[n], acc[m][n], 0, 0, 0);
    __syncthreads();
  }
  // C/D layout (verified m89): col = lane&15, row = (lane>>4)*4 + reg
  const int crow0 = bm + wm + ((lane >> 4) << 2);
  const int ccol0 = bn + wn + (lane & 15);
  #pragma unroll
  for (int m = 0; m < 4; ++m) {
    #pragma unroll
    for (int r = 0; r < 4; ++r) {
      const int rr = crow0 + m * 16 + r;
      const int orow = permute ? ((rr % SQ) * BB + (rr / SQ)) : rr;
      float* cp = C + (size_t)orow * N + ccol0;
      #pragma unroll
      for (int n = 0; n < 4; ++n) cp[n * 16] = acc[m][n][r];
    }
  }
}

// ---------------------------------------------------------------------------
// Fused attention per (b,n), b-major qkv chunk. 384 threads: thread (i, half)
// processes q-row i over j in [half*96, half*96+96) with its own online
// softmax; halves merged through reused LDS at the end.
// rel_shift map: t=(j+191-i) mod 193; t==192 -> 0; row = (j<=i ? i : i+1).
// ---------------------------------------------------------------------------
__global__ __launch_bounds__(384) void attn_kernel(
    const float* __restrict__ qkv_c, const float* __restrict__ rhk,
    const float* __restrict__ rwb, const float* __restrict__ rrb,
    float* __restrict__ av_c) {
  __shared__ __align__(16) float ks[SQ * DH];        // broadcast reads only
  __shared__ __align__(16) float rs[SQ * (DH + 1)];  // lane-varying rows -> pad
  __shared__ __align__(16) float vs[SQ * DH];        // broadcast reads only
  __shared__ float kbs[SQ];
  __shared__ float rbs[SQ];
  const int bid = blockIdx.x;
  const int n = bid & 7;
  const int bl = bid >> 3;          // local batch index in chunk
  const int tid = threadIdx.x;
  const int i = (tid < SQ) ? tid : tid - SQ;
  const int half = (tid < SQ) ? 0 : 1;

  for (int it = tid; it < SQ * (DH / 4); it += 384) {
    const int j = it >> 4;
    const int c = (it & 15) << 2;
    const float* base = qkv_c + ((size_t)bl * SQ + j) * (3 * DM) + n * DH + c;
    const float4 kv = *reinterpret_cast<const float4*>(base + DM);
    const float4 vv = *reinterpret_cast<const float4*>(base + 2 * DM);
    const float4 rv = *reinterpret_cast<const float4*>(rhk + (size_t)j * DM + n * DH + c);
    *reinterpret_cast<float4*>(&ks[j * DH + c]) = kv;
    *reinterpret_cast<float4*>(&vs[j * DH + c]) = vv;
    rs[j * (DH + 1) + c + 0] = rv.x;
    rs[j * (DH + 1) + c + 1] = rv.y;
    rs[j * (DH + 1) + c + 2] = rv.z;
    rs[j * (DH + 1) + c + 3] = rv.w;
  }
  __syncthreads();
  if (tid < SQ) {
    float ak = 0.f, ar = 0.f;
    #pragma unroll
    for (int d = 0; d < DH; ++d) {
      ak += rwb[n * DH + d] * ks[tid * DH + d];
      ar += rrb[n * DH + d] * rs[tid * (DH + 1) + d];
    }
    kbs[tid] = ak; rbs[tid] = ar;
  }
  float qi[DH], qp[DH];
  {
    const float* q0 = qkv_c + ((size_t)bl * SQ + i) * (3 * DM) + n * DH;
    const int i2 = (i < SQ - 1) ? i + 1 : i;
    const float* q1 = qkv_c + ((size_t)bl * SQ + i2) * (3 * DM) + n * DH;
    #pragma unroll
    for (int d4 = 0; d4 < DH / 4; ++d4) {
      const float4 t0 = reinterpret_cast<const float4*>(q0)[d4];
      qi[d4*4+0] = t0.x; qi[d4*4+1] = t0.y; qi[d4*4+2] = t0.z; qi[d4*4+3] = t0.w;
      const float4 t1 = reinterpret_cast<const float4*>(q1)[d4];
      qp[d4*4+0] = t1.x; qp[d4*4+1] = t1.y; qp[d4*4+2] = t1.z; qp[d4*4+3] = t1.w;
    }
  }
  __syncthreads();   // bias tables visible

  float m = -1e30f, l = 0.f;
  float acc[DH];
  #pragma unroll
  for (int d = 0; d < DH; ++d) acc[d] = 0.f;

  const int j0 = half * (SQ / 2);
  for (int jj = 0; jj < SQ / 2; ++jj) {
    const int j = j0 + jj;
    int t = j + (SQ - 1) - i;
    if (t >= SQ + 1) t -= (SQ + 1);          // mod 193
    const bool valid = (t != SQ);            // t==192 -> zero BD
    const int tt = valid ? t : 0;
    float ac = 0.f, bd1 = 0.f, bd2 = 0.f;
    #pragma unroll
    for (int d4 = 0; d4 < DH / 4; ++d4) {
      const float4 kv = *reinterpret_cast<const float4*>(&ks[j * DH + d4 * 4]);
      ac += qi[d4*4+0]*kv.x + qi[d4*4+1]*kv.y + qi[d4*4+2]*kv.z + qi[d4*4+3]*kv.w;
    }
    #pragma unroll
    for (int d = 0; d < DH; ++d) {
      const float rv = rs[tt * (DH + 1) + d];
      bd1 += qi[d] * rv;
      bd2 += qp[d] * rv;
    }
    const float bd = (j <= i) ? bd1 : bd2;
    float sv = ac + kbs[j] + (valid ? (bd + rbs[tt]) : 0.f);
    sv *= ASCALE;
    const bool upd = sv > m;
    const float mn = upd ? sv : m;
    const float f2 = upd ? __expf(m - sv) : 1.0f;
    const float e = __expf(sv - mn);
    l = l * f2 + e;
    m = mn;
    #pragma unroll
    for (int d4 = 0; d4 < DH / 4; ++d4) {
      const float4 vv = *reinterpret_cast<const float4*>(&vs[j * DH + d4 * 4]);
      acc[d4*4+0] = acc[d4*4+0] * f2 + e * vv.x;
      acc[d4*4+1] = acc[d4*4+1] * f2 + e * vv.y;
      acc[d4*4+2] = acc[d4*4+2] * f2 + e * vv.z;
      acc[d4*4+3] = acc[d4*4+3] * f2 + e * vv.w;
    }
  }

  // merge halves: upper half parks partials in reused LDS (ks/kbs/rbs)
  __syncthreads();
  if (half == 1) {
    kbs[i] = m; rbs[i] = l;
    #pragma unroll
    for (int d = 0; d < DH; ++d) ks[i * DH + d] = acc[d];
  }
  __syncthreads();
  if (half == 0) {
    const float m1 = kbs[i], l1 = rbs[i];
    const float M = fmaxf(m, m1);
    const float e0 = __expf(m - M);
    const float e1 = __expf(m1 - M);
    const float inv = 1.0f / (l * e0 + l1 * e1);
    float* op = av_c + ((size_t)bl * SQ + i) * DM + n * DH;
    #pragma unroll
    for (int d4 = 0; d4 < DH / 4; ++d4) {
      float4 o;
      o.x = (acc[d4*4+0] * e0 + ks[i * DH + d4*4+0] * e1) * inv;
      o.y = (acc[d4*4+1] * e0 + ks[i * DH + d4*4+1] * e1) * inv;
      o.z = (acc[d4*4+2] * e0 + ks[i * DH + d4*4+2] * e1) * inv;
      o.w = (acc[d4*4+3] * e0 + ks[i * DH + d4*4+3] * e1) * inv;
      reinterpret_cast<float4*>(op)[d4] = o;
    }
  }
}

// ---------------------------------------------------------------------------
extern "C" void kernel_launch(void* const* d_in, const int* in_sizes, int n_in,
                              void* d_out, int out_size, void* d_ws, size_t ws_size,
                              hipStream_t stream) {
  const float* inp   = (const float*)d_in[0];
  const float* ln1_g = (const float*)d_in[1];
  const float* ln1_b = (const float*)d_in[2];
  const float* ln2_g = (const float*)d_in[3];
  const float* ln2_b = (const float*)d_in[4];
  const float* Wqkv  = (const float*)d_in[5];
  const float* Wr    = (const float*)d_in[6];
  const float* Wo    = (const float*)d_in[7];
  const float* rwb   = (const float*)d_in[8];
  const float* rrb   = (const float*)d_in[9];
  float* out = (float*)d_out;

  float* hprime = out;   // b-major LN output parked in d_out (dead before final GEMM)

  // largest batch-chunk whose footprint fits ws_size (deterministic host math)
  const int cands[4] = {192, 96, 48, 24};
  int CB = 24;
  for (int ci = 0; ci < 4; ++ci) {
    const int c = cands[ci];
    const size_t need = (size_t)c * SQ * 3072     // hb_c  (bf16 Mc x 1536)
                      + (size_t)c * SQ * 6144     // qkv_c (fp32 Mc x 1536)
                      + (size_t)c * SQ * 2048     // av_c  (fp32 Mc x 512)
                      + (size_t)BB * SQ * 3072    // avb   (bf16 full M x 1536)
                      + 4718592 + 1572864         // Wqkvb + Wob
                      + 786432;                   // pe + rhk
    if (need <= ws_size) { CB = c; break; }
  }

  char* p = (char*)d_ws;
  unsigned short* hb_c  = (unsigned short*)p; p += (size_t)CB * SQ * 3072;
  float*          qkv_c = (float*)p;          p += (size_t)CB * SQ * 6144;
  float*          av_c  = (float*)p;          p += (size_t)CB * SQ * 2048;
  unsigned short* avb   = (unsigned short*)p; p += (size_t)BB * SQ * 3072;
  unsigned short* Wqkvb = (unsigned short*)p; p += 4718592;
  unsigned short* Wob   = (unsigned short*)p; p += 1572864;
  float*          pe    = (float*)p;          p += (size_t)BB * DM * 4;
  float*          rhk   = (float*)p;

  ln2_kernel<<<SQ * BB, 128, 0, stream>>>(inp, ln1_g, ln1_b, ln2_g, ln2_b, hprime);
  posemb_kernel<<<(BB * DM + 255) / 256, 256, 0, stream>>>(inp, pe);
  rhk_kernel<<<dim3(BB, DM / 256), 256, 0, stream>>>(pe, Wr, rhk);
  conv_split_kernel<<<(3 * DM * DM) / 256, 256, 0, stream>>>(Wqkv, Wqkvb, 3 * DM, 1);
  conv_split_kernel<<<(DM * DM) / 256, 256, 0, stream>>>(Wo, Wob, DM, 1);

  for (int b0 = 0; b0 < BB; b0 += CB) {
    const int Mc = CB * SQ;
    conv_split_kernel<<<(Mc * DM) / 256, 256, 0, stream>>>(
        hprime + (size_t)b0 * SQ * DM, hb_c, Mc, 0);
    gemm_mfma<<<dim3(K3 / 128, Mc / 128), 256, 0, stream>>>(
        hb_c, Wqkvb, qkv_c, K3, K3, 0);
    attn_kernel<<<CB * NH, 384, 0, stream>>>(qkv_c, rhk, rwb, rrb, av_c);
    conv_split_kernel<<<(Mc * DM) / 256, 256, 0, stream>>>(
        av_c, avb + (size_t)b0 * SQ * K3, Mc, 0);
  }

  // out[s*B+b] = av[b*S+s] . Wo^T  (row-permuted C write, runs after h' dead)
  gemm_mfma<<<dim3(DM / 128, (BB * SQ) / 128), 256, 0, stream>>>(
      avb, Wob, out, DM, K3, 1);
}

// Round 5
// 516.381 us; speedup vs baseline: 7.3881x; 7.3881x over previous
//
#include <hip/hip_runtime.h>
#include <math.h>

#define SQ 192      // S
#define BB 192      // B
#define DM 512
#define NH 8
#define DH 64
#define NEPS 1e-5f
#define ASCALE 0.125f   // 1/sqrt(64)

typedef __bf16 bf16x8 __attribute__((ext_vector_type(8)));
typedef float f32x4 __attribute__((ext_vector_type(4)));
typedef unsigned short u16x8 __attribute__((ext_vector_type(8)));

__device__ __forceinline__ void gload16(const unsigned short* g, unsigned short* l) {
  __builtin_amdgcn_global_load_lds(
      (const __attribute__((address_space(1))) void*)g,
      (__attribute__((address_space(3))) void*)l, 16, 0, 0);
}
__device__ __forceinline__ unsigned short f2b(float x) {   // fp32 -> bf16 bits (RNE)
  union { float f; unsigned u; } c; c.f = x;
  return (unsigned short)((c.u + 0x7fffu + ((c.u >> 16) & 1u)) >> 16);
}
__device__ __forceinline__ float f2bf(float x) {           // round-to-bf16, keep fp32
  union { float f; unsigned u; } c; c.f = x;
  c.u = (c.u + 0x7fffu + ((c.u >> 16) & 1u)) & 0xffff0000u;
  return c.f;
}
__device__ __forceinline__ float b2f(unsigned short h) {
  union { unsigned u; float f; } c; c.u = ((unsigned)h) << 16;
  return c.f;
}

// ---------------------------------------------------------------------------
// Fused double LayerNorm -> split bf16 planes (b-major rows b*S+s).
// Planes live in d_out (dead before final out-GEMM overwrites it).
// ---------------------------------------------------------------------------
__global__ __launch_bounds__(128) void ln2_kernel(
    const float* __restrict__ inp, const float* __restrict__ g1, const float* __restrict__ b1,
    const float* __restrict__ g2, const float* __restrict__ b2,
    unsigned short* __restrict__ hbhi, unsigned short* __restrict__ hblo) {
  const int R = blockIdx.x;              // input row s*B+b
  const int s = R / BB;
  const int b = R % BB;
  const int t = threadIdx.x;
  const float4 v = reinterpret_cast<const float4*>(inp + (size_t)R * DM)[t];
  float sum  = v.x + v.y + v.z + v.w;
  float sum2 = v.x*v.x + v.y*v.y + v.z*v.z + v.w*v.w;
  #pragma unroll
  for (int o = 32; o >= 1; o >>= 1) { sum += __shfl_xor(sum, o); sum2 += __shfl_xor(sum2, o); }
  __shared__ float red[2][2];
  const int wv = t >> 6;
  if ((t & 63) == 0) { red[0][wv] = sum; red[1][wv] = sum2; }
  __syncthreads();
  sum = red[0][0] + red[0][1]; sum2 = red[1][0] + red[1][1];
  float mu = sum * (1.0f / DM);
  float var = sum2 * (1.0f / DM) - mu * mu;
  float rstd = rsqrtf(var + NEPS);
  const float4 G1 = reinterpret_cast<const float4*>(g1)[t];
  const float4 B1 = reinterpret_cast<const float4*>(b1)[t];
  float4 x;
  x.x = (v.x - mu) * rstd * G1.x + B1.x;
  x.y = (v.y - mu) * rstd * G1.y + B1.y;
  x.z = (v.z - mu) * rstd * G1.z + B1.z;
  x.w = (v.w - mu) * rstd * G1.w + B1.w;
  sum  = x.x + x.y + x.z + x.w;
  sum2 = x.x*x.x + x.y*x.y + x.z*x.z + x.w*x.w;
  #pragma unroll
  for (int o = 32; o >= 1; o >>= 1) { sum += __shfl_xor(sum, o); sum2 += __shfl_xor(sum2, o); }
  __syncthreads();
  if ((t & 63) == 0) { red[0][wv] = sum; red[1][wv] = sum2; }
  __syncthreads();
  sum = red[0][0] + red[0][1]; sum2 = red[1][0] + red[1][1];
  mu = sum * (1.0f / DM);
  var = sum2 * (1.0f / DM) - mu * mu;
  rstd = rsqrtf(var + NEPS);
  const float4 G2 = reinterpret_cast<const float4*>(g2)[t];
  const float4 B2 = reinterpret_cast<const float4*>(b2)[t];
  float4 o4;
  o4.x = (x.x - mu) * rstd * G2.x + B2.x;
  o4.y = (x.y - mu) * rstd * G2.y + B2.y;
  o4.z = (x.z - mu) * rstd * G2.z + B2.z;
  o4.w = (x.w - mu) * rstd * G2.w + B2.w;
  const size_t orow = (size_t)b * SQ + s;
  ushort4 hh, ll;
  hh.x = f2b(o4.x); ll.x = f2b(o4.x - f2bf(o4.x));
  hh.y = f2b(o4.y); ll.y = f2b(o4.y - f2bf(o4.y));
  hh.z = f2b(o4.z); ll.z = f2b(o4.z - f2bf(o4.z));
  hh.w = f2b(o4.w); ll.w = f2b(o4.w - f2bf(o4.w));
  *reinterpret_cast<ushort4*>(hbhi + orow * DM + t * 4) = hh;
  *reinterpret_cast<ushort4*>(hblo + orow * DM + t * 4) = ll;
}

// ---------------------------------------------------------------------------
__global__ void posemb_kernel(const float* __restrict__ inp, float* __restrict__ pe) {
  const int idx = blockIdx.x * 256 + threadIdx.x;
  if (idx >= BB * DM) return;
  const int b = idx >> 9;
  const int d = idx & 511;
  const float ps = inp[(size_t)b * DM];
  const int i = (d < 256) ? d : (d - 256);
  const float invf = expf(-9.210340371976184f * (float)i * (1.0f / 256.0f));
  const float a = ps * invf;
  pe[idx] = (d < 256) ? sinf(a) : cosf(a);
}

// ---------------------------------------------------------------------------
// r_head_k[j][e] = sum_d pos_emb[j][d] * W_r[e][d]  -> bf16 (hi) plane [192][512]
// ---------------------------------------------------------------------------
__global__ __launch_bounds__(256) void rhk_kernel(
    const float* __restrict__ pe, const float* __restrict__ Wr, unsigned short* __restrict__ rhkb) {
  __shared__ __align__(16) float pr[DM];
  const int j = blockIdx.x;
  const int e = blockIdx.y * 256 + threadIdx.x;
  for (int d = threadIdx.x; d < DM; d += 256) pr[d] = pe[(size_t)j * DM + d];
  __syncthreads();
  const float4* w4 = reinterpret_cast<const float4*>(Wr + (size_t)e * DM);
  const float4* p4 = reinterpret_cast<const float4*>(pr);
  float acc = 0.f;
  #pragma unroll 8
  for (int d4 = 0; d4 < DM / 4; ++d4) {
    const float4 a = p4[d4];
    const float4 w = w4[d4];
    acc += a.x*w.x + a.y*w.y + a.z*w.z + a.w*w.w;
  }
  rhkb[(size_t)j * DM + e] = f2b(acc);
}

// ---------------------------------------------------------------------------
__global__ void convhi_kernel(const float* __restrict__ src, unsigned short* __restrict__ dst, int nel) {
  const int i = blockIdx.x * 256 + threadIdx.x;
  if (i < nel) dst[i] = f2b(src[i]);
}

// ---------------------------------------------------------------------------
// Split-bf16 NT MFMA GEMM, K' = 1024 ([Ahi|Alo] . [Bhi|Bhi]^T).
// 128x128 tile, BK=64, 256 thr (4 waves 2x2), double-buffered LDS,
// XOR-swizzled source (slot ^= row&7) so frag ds_read_b128 is conflict-free.
// mode 0: C -> split planes Chi[.][1536] (+ Clo[.][512] for col<512)
// mode 1: C -> fp32 Cf with row permute (rr%SQ)*BB + rr/SQ, width N.
// ---------------------------------------------------------------------------
__global__ __launch_bounds__(256, 2) void gemm_mfma(
    const unsigned short* __restrict__ Ahi, const unsigned short* __restrict__ Alo,
    const unsigned short* __restrict__ Bp,
    unsigned short* __restrict__ Chi, unsigned short* __restrict__ Clo,
    float* __restrict__ Cf, int N, int mode) {
  __shared__ __align__(16) unsigned short As[2][128][64];
  __shared__ __align__(16) unsigned short Bs[2][128][64];
  const int tid = threadIdx.x;
  // bijective XCD swizzle (nwg % 8 == 0 for all our grids)
  const int nwg = gridDim.x * gridDim.y;
  int flat = blockIdx.y * gridDim.x + blockIdx.x;
  flat = (flat & 7) * (nwg >> 3) + (flat >> 3);
  const int bm = (flat / gridDim.x) * 128;
  const int bn = (flat % gridDim.x) * 128;
  const int lane = tid & 63, wv = tid >> 6;
  const int wm = (wv >> 1) << 6, wn = (wv & 1) << 6;
  const int fr = lane & 15, q4 = lane >> 4;
  const int srow_ = tid >> 3, sl = tid & 7;

  f32x4 acc[4][4];
  #pragma unroll
  for (int mt = 0; mt < 4; ++mt)
    #pragma unroll
    for (int nt = 0; nt < 4; ++nt) acc[mt][nt] = (f32x4){0.f, 0.f, 0.f, 0.f};

  auto STAGE = [&](int buf, int k0) {
    const unsigned short* Ap = (k0 < 512) ? Ahi : Alo;
    const int kk = k0 & 511;
    #pragma unroll
    for (int it = 0; it < 4; ++it) {
      const int row = it * 32 + srow_;
      const int sp = (sl ^ (row & 7)) << 3;
      gload16(Ap + (size_t)(bm + row) * 512 + kk + sp, &As[buf][row][sl << 3]);
      gload16(Bp + (size_t)(bn + row) * 512 + kk + sp, &Bs[buf][row][sl << 3]);
    }
  };

  STAGE(0, 0);
  __syncthreads();
  int buf = 0;
  for (int step = 0; step < 16; ++step) {
    if (step < 15) STAGE(buf ^ 1, (step + 1) * 64);
    bf16x8 a[4][2], bb[4][2];
    #pragma unroll
    for (int mt = 0; mt < 4; ++mt)
      #pragma unroll
      for (int kc = 0; kc < 2; ++kc) {
        const int ra = wm + mt * 16 + fr;
        a[mt][kc]  = *reinterpret_cast<const bf16x8*>(&As[buf][ra][((((kc << 2) | q4) ^ (ra & 7)) << 3)]);
        const int rb = wn + mt * 16 + fr;
        bb[mt][kc] = *reinterpret_cast<const bf16x8*>(&Bs[buf][rb][((((kc << 2) | q4) ^ (rb & 7)) << 3)]);
      }
    #pragma unroll
    for (int mt = 0; mt < 4; ++mt)
      #pragma unroll
      for (int nt = 0; nt < 4; ++nt) {
        acc[mt][nt] = __builtin_amdgcn_mfma_f32_16x16x32_bf16(a[mt][0], bb[nt][0], acc[mt][nt], 0, 0, 0);
        acc[mt][nt] = __builtin_amdgcn_mfma_f32_16x16x32_bf16(a[mt][1], bb[nt][1], acc[mt][nt], 0, 0, 0);
      }
    __syncthreads();
    buf ^= 1;
  }
  // C/D layout: col = lane&15, row = (lane>>4)*4 + reg (verified m89)
  const int crow0 = bm + wm + (q4 << 2);
  const int ccol0 = bn + wn + fr;
  if (mode == 0) {
    #pragma unroll
    for (int mt = 0; mt < 4; ++mt)
      #pragma unroll
      for (int r = 0; r < 4; ++r) {
        const size_t rr = crow0 + mt * 16 + r;
        #pragma unroll
        for (int nt = 0; nt < 4; ++nt) {
          const int col = ccol0 + nt * 16;
          const float v = acc[mt][nt][r];
          Chi[rr * 1536 + col] = f2b(v);
          if (col < 512) Clo[rr * 512 + col] = f2b(v - f2bf(v));
        }
      }
  } else {
    #pragma unroll
    for (int mt = 0; mt < 4; ++mt)
      #pragma unroll
      for (int r = 0; r < 4; ++r) {
        const int rr = crow0 + mt * 16 + r;
        const size_t orow = (size_t)(rr % SQ) * BB + (rr / SQ);
        #pragma unroll
        for (int nt = 0; nt < 4; ++nt)
          Cf[orow * N + ccol0 + nt * 16] = acc[mt][nt][r];
      }
  }
}

// ---------------------------------------------------------------------------
// MFMA attention per (b,n). 384 thr = 6 waves; wave w owns q-rows [32w,32w+32).
// U = (q~)R^T -> LDS bf16; AC = (q~)K^T in regs; rel-shift gather + softmax;
// P -> LDS bf16; PV via MFMA vs transposed V. Writes split-bf16 av planes.
// qkvhi/qlo are chunk-local (rows bl*SQ+s); av planes are global (b0+bl).
// LDS (shorts): QHI[0) QLO[12288) KR[24576) UP[36864, pitch 200) tbl@75264.
// ---------------------------------------------------------------------------
#define QLO0 12288
#define KR0  24576
#define UP0  36864
#define TBL0 75264
#define UPITCH 200

__global__ __launch_bounds__(384) void attn_mfma(
    const unsigned short* __restrict__ qkvhi,  // [CB*192][1536]
    const unsigned short* __restrict__ qlo,    // [CB*192][512]
    const unsigned short* __restrict__ rhkb,   // [192][512]
    const float* __restrict__ rwb, const float* __restrict__ rrb,
    unsigned short* __restrict__ avhi, unsigned short* __restrict__ avlo, int b0) {
  __shared__ __align__(16) unsigned short lds[76032];
  float* tbl = reinterpret_cast<float*>(&lds[TBL0]);   // kb[0..191], rb[192..383]
  const int bid = blockIdx.x;
  const int n = bid & 7, bl = bid >> 3;
  const int tid = threadIdx.x;
  const int lane = tid & 63, wv = tid >> 6;
  const int fr = lane & 15, q4 = lane >> 4;
  const int m0 = wv << 5;
  const size_t rin = (size_t)bl * SQ;            // chunk-local row base
  const size_t rout = (size_t)(b0 + bl) * SQ;    // global row base

  // stage QHI, QLO, RHI (swizzled source -> linear LDS)
  #pragma unroll
  for (int it = 0; it < 4; ++it) {
    const int u = it * 384 + tid;
    const int row = u >> 3, sl = u & 7, sp = (sl ^ (row & 7)) << 3;
    gload16(qkvhi + (rin + row) * 1536 + n * 64 + sp, &lds[(row << 6) + (sl << 3)]);
    gload16(qlo + (rin + row) * 512 + n * 64 + sp, &lds[QLO0 + (row << 6) + (sl << 3)]);
    gload16(rhkb + (size_t)row * 512 + n * 64 + sp, &lds[KR0 + (row << 6) + (sl << 3)]);
  }
  // prefetch K and V into regs
  u16x8 kreg[4];
  #pragma unroll
  for (int it = 0; it < 4; ++it) {
    const int u = it * 384 + tid;
    const int row = u >> 3, sl = u & 7;
    kreg[it] = *reinterpret_cast<const u16x8*>(qkvhi + (rin + row) * 1536 + 512 + n * 64 + (sl << 3));
  }
  const int vj = tid % 192, vdg = tid / 192;
  u16x8 vreg[4];
  #pragma unroll
  for (int c = 0; c < 4; ++c)
    vreg[c] = *reinterpret_cast<const u16x8*>(qkvhi + (rin + vj) * 1536 + 1024 + n * 64 + vdg * 32 + c * 8);
  __syncthreads();

  // rb table from RHI
  if (tid < SQ) {
    float a = 0.f;
    #pragma unroll
    for (int s = 0; s < 8; ++s) {
      const u16x8 rv = *reinterpret_cast<const u16x8*>(&lds[KR0 + (tid << 6) + ((s ^ (tid & 7)) << 3)]);
      #pragma unroll
      for (int e = 0; e < 8; ++e) a += rrb[n * 64 + s * 8 + e] * b2f(rv[e]);
    }
    tbl[192 + tid] = a;
  }
  // Q A-fragments (reused by U and AC phases)
  bf16x8 ahi[2][2], alo_[2][2];
  #pragma unroll
  for (int mt = 0; mt < 2; ++mt)
    #pragma unroll
    for (int kc = 0; kc < 2; ++kc) {
      const int r_ = m0 + mt * 16 + fr;
      const int sp = ((((kc << 2) | q4) ^ (r_ & 7)) << 3);
      ahi[mt][kc]  = *reinterpret_cast<const bf16x8*>(&lds[(r_ << 6) + sp]);
      alo_[mt][kc] = *reinterpret_cast<const bf16x8*>(&lds[QLO0 + (r_ << 6) + sp]);
    }
  // U = Q~ . R^T
  f32x4 acc[2][12];
  #pragma unroll
  for (int mt = 0; mt < 2; ++mt)
    #pragma unroll
    for (int nt = 0; nt < 12; ++nt) acc[mt][nt] = (f32x4){0.f, 0.f, 0.f, 0.f};
  #pragma unroll
  for (int nt = 0; nt < 12; ++nt) {
    bf16x8 bbr[2];
    #pragma unroll
    for (int kc = 0; kc < 2; ++kc) {
      const int r_ = nt * 16 + fr;
      bbr[kc] = *reinterpret_cast<const bf16x8*>(&lds[KR0 + (r_ << 6) + ((((kc << 2) | q4) ^ (r_ & 7)) << 3)]);
    }
    #pragma unroll
    for (int mt = 0; mt < 2; ++mt) {
      acc[mt][nt] = __builtin_amdgcn_mfma_f32_16x16x32_bf16(ahi[mt][0], bbr[0], acc[mt][nt], 0, 0, 0);
      acc[mt][nt] = __builtin_amdgcn_mfma_f32_16x16x32_bf16(ahi[mt][1], bbr[1], acc[mt][nt], 0, 0, 0);
      acc[mt][nt] = __builtin_amdgcn_mfma_f32_16x16x32_bf16(alo_[mt][0], bbr[0], acc[mt][nt], 0, 0, 0);
      acc[mt][nt] = __builtin_amdgcn_mfma_f32_16x16x32_bf16(alo_[mt][1], bbr[1], acc[mt][nt], 0, 0, 0);
    }
  }
  // write U (bf16)
  #pragma unroll
  for (int mt = 0; mt < 2; ++mt)
    #pragma unroll
    for (int nt = 0; nt < 12; ++nt)
      #pragma unroll
      for (int r = 0; r < 4; ++r) {
        const int i = m0 + mt * 16 + (q4 << 2) + r;
        lds[UP0 + i * UPITCH + nt * 16 + fr] = f2b(acc[mt][nt][r]);
      }
  __syncthreads();   // U + rb visible; all RHI/Q reads done

  // K into KR slot (swizzled ds_write)
  #pragma unroll
  for (int it = 0; it < 4; ++it) {
    const int u = it * 384 + tid;
    const int row = u >> 3, sl = u & 7;
    *reinterpret_cast<u16x8*>(&lds[KR0 + (row << 6) + ((sl ^ (row & 7)) << 3)]) = kreg[it];
  }
  __syncthreads();   // K visible

  // kb table
  if (tid < SQ) {
    float a = 0.f;
    #pragma unroll
    for (int s = 0; s < 8; ++s) {
      const u16x8 kv = *reinterpret_cast<const u16x8*>(&lds[KR0 + (tid << 6) + ((s ^ (tid & 7)) << 3)]);
      #pragma unroll
      for (int e = 0; e < 8; ++e) a += rwb[n * 64 + s * 8 + e] * b2f(kv[e]);
    }
    tbl[tid] = a;
  }
  // AC = Q~ . K^T
  #pragma unroll
  for (int mt = 0; mt < 2; ++mt)
    #pragma unroll
    for (int nt = 0; nt < 12; ++nt) acc[mt][nt] = (f32x4){0.f, 0.f, 0.f, 0.f};
  #pragma unroll
  for (int nt = 0; nt < 12; ++nt) {
    bf16x8 bbr[2];
    #pragma unroll
    for (int kc = 0; kc < 2; ++kc) {
      const int r_ = nt * 16 + fr;
      bbr[kc] = *reinterpret_cast<const bf16x8*>(&lds[KR0 + (r_ << 6) + ((((kc << 2) | q4) ^ (r_ & 7)) << 3)]);
    }
    #pragma unroll
    for (int mt = 0; mt < 2; ++mt) {
      acc[mt][nt] = __builtin_amdgcn_mfma_f32_16x16x32_bf16(ahi[mt][0], bbr[0], acc[mt][nt], 0, 0, 0);
      acc[mt][nt] = __builtin_amdgcn_mfma_f32_16x16x32_bf16(ahi[mt][1], bbr[1], acc[mt][nt], 0, 0, 0);
      acc[mt][nt] = __builtin_amdgcn_mfma_f32_16x16x32_bf16(alo_[mt][0], bbr[0], acc[mt][nt], 0, 0, 0);
      acc[mt][nt] = __builtin_amdgcn_mfma_f32_16x16x32_bf16(alo_[mt][1], bbr[1], acc[mt][nt], 0, 0, 0);
    }
  }
  // Vt stage into [0, 12800): Vt[d][j], pitch UPITCH (QHI/QLO dead)
  #pragma unroll
  for (int c = 0; c < 4; ++c)
    #pragma unroll
    for (int e = 0; e < 8; ++e)
      lds[(vdg * 32 + c * 8 + e) * UPITCH + vj] = vreg[c][e];
  __syncthreads();   // kb + Vt visible; gather may begin

  // rel-shift gather + row softmax (rounded-p stashed back into acc)
  float linv[2][4];
  #pragma unroll
  for (int mt = 0; mt < 2; ++mt) {
    #pragma unroll
    for (int r = 0; r < 4; ++r) {
      const int i = m0 + mt * 16 + (q4 << 2) + r;
      float sr[12];
      #pragma unroll
      for (int nt = 0; nt < 12; ++nt) {
        const int j = nt * 16 + fr;
        const int t = j + 191 - i;
        float g;
        if (t <= 191)      g = b2f(lds[UP0 + i * UPITCH + t]) + tbl[192 + t];
        else if (t == 192) g = 0.f;
        else { const int t2 = t - 193; g = b2f(lds[UP0 + (i + 1) * UPITCH + t2]) + tbl[192 + t2]; }
        sr[nt] = acc[mt][nt][r] + tbl[j] + g;
      }
      float mx = sr[0];
      #pragma unroll
      for (int nt = 1; nt < 12; ++nt) mx = fmaxf(mx, sr[nt]);
      #pragma unroll
      for (int o = 1; o <= 8; o <<= 1) mx = fmaxf(mx, __shfl_xor(mx, o));
      float ls = 0.f;
      #pragma unroll
      for (int nt = 0; nt < 12; ++nt) {
        float p = f2bf(__expf((sr[nt] - mx) * ASCALE));
        ls += p;
        acc[mt][nt][r] = p;
      }
      #pragma unroll
      for (int o = 1; o <= 8; o <<= 1) ls += __shfl_xor(ls, o);
      linv[mt][r] = 1.0f / ls;
    }
  }
  __syncthreads();   // all U gathers done -> safe to overwrite with P

  #pragma unroll
  for (int mt = 0; mt < 2; ++mt)
    #pragma unroll
    for (int nt = 0; nt < 12; ++nt)
      #pragma unroll
      for (int r = 0; r < 4; ++r) {
        const int i = m0 + mt * 16 + (q4 << 2) + r;
        lds[UP0 + i * UPITCH + nt * 16 + fr] = f2b(acc[mt][nt][r]);
      }
  __syncthreads();   // P visible

  // PV: out[i][d] = sum_j P[i][j] Vt[d][j]
  f32x4 o2[2][4];
  #pragma unroll
  for (int mt = 0; mt < 2; ++mt)
    #pragma unroll
    for (int nt = 0; nt < 4; ++nt) o2[mt][nt] = (f32x4){0.f, 0.f, 0.f, 0.f};
  #pragma unroll
  for (int kc = 0; kc < 6; ++kc) {
    bf16x8 pa[2];
    #pragma unroll
    for (int mt = 0; mt < 2; ++mt) {
      const int r_ = m0 + mt * 16 + fr;
      pa[mt] = *reinterpret_cast<const bf16x8*>(&lds[UP0 + r_ * UPITCH + kc * 32 + (q4 << 3)]);
    }
    #pragma unroll
    for (int nt = 0; nt < 4; ++nt) {
      const int d_ = nt * 16 + fr;
      const bf16x8 vb = *reinterpret_cast<const bf16x8*>(&lds[d_ * UPITCH + kc * 32 + (q4 << 3)]);
      #pragma unroll
      for (int mt = 0; mt < 2; ++mt)
        o2[mt][nt] = __builtin_amdgcn_mfma_f32_16x16x32_bf16(pa[mt], vb, o2[mt][nt], 0, 0, 0);
    }
  }
  // normalize + store split planes (global rows)
  #pragma unroll
  for (int mt = 0; mt < 2; ++mt)
    #pragma unroll
    for (int nt = 0; nt < 4; ++nt)
      #pragma unroll
      for (int r = 0; r < 4; ++r) {
        const int i = m0 + mt * 16 + (q4 << 2) + r;
        const int col = n * 64 + nt * 16 + fr;
        const float v = o2[mt][nt][r] * linv[mt][r];
        avhi[(rout + i) * 512 + col] = f2b(v);
        avlo[(rout + i) * 512 + col] = f2b(v - f2bf(v));
      }
}

// ---------------------------------------------------------------------------
extern "C" void kernel_launch(void* const* d_in, const int* in_sizes, int n_in,
                              void* d_out, int out_size, void* d_ws, size_t ws_size,
                              hipStream_t stream) {
  const float* inp   = (const float*)d_in[0];
  const float* ln1_g = (const float*)d_in[1];
  const float* ln1_b = (const float*)d_in[2];
  const float* ln2_g = (const float*)d_in[3];
  const float* ln2_b = (const float*)d_in[4];
  const float* Wqkv  = (const float*)d_in[5];
  const float* Wr    = (const float*)d_in[6];
  const float* Wo    = (const float*)d_in[7];
  const float* rwb   = (const float*)d_in[8];
  const float* rrb   = (const float*)d_in[9];
  float* out = (float*)d_out;

  const size_t M = (size_t)SQ * BB;   // 36864

  // LN split planes parked in d_out (exactly out_size*4 bytes; dead before
  // the final out-GEMM fully overwrites d_out).
  unsigned short* hbhi = (unsigned short*)d_out;
  unsigned short* hblo = hbhi + M * DM;

  // adaptive batch-chunk: footprint = fixed 74.6MB + CB*0.786MB (ws >= 172MB
  // proven by round-3 run => CB >= 96 guaranteed).
  const int cands[4] = {192, 96, 48, 24};
  int CB = 24;
  for (int ci = 0; ci < 4; ++ci) {
    const int c = cands[ci];
    const size_t need = (size_t)c * SQ * 1536 * 2    // qhi_c
                      + (size_t)c * SQ * 512 * 2     // qlo_c
                      + 2 * M * 512 * 2              // avhi + avlo
                      + 1536 * 512 * 2 + 512 * 512 * 2   // Wqb + Wob
                      + (size_t)BB * DM * 4 + (size_t)BB * DM * 2;  // pe + rhkb
    if (need <= ws_size) { CB = c; break; }
  }

  char* p = (char*)d_ws;
  unsigned short* qhi  = (unsigned short*)p; p += (size_t)CB * SQ * 1536 * 2;
  unsigned short* qloP = (unsigned short*)p; p += (size_t)CB * SQ * 512 * 2;
  unsigned short* avhi = (unsigned short*)p; p += M * 512 * 2;
  unsigned short* avlo = (unsigned short*)p; p += M * 512 * 2;
  unsigned short* Wqb  = (unsigned short*)p; p += (size_t)1536 * 512 * 2;
  unsigned short* Wob  = (unsigned short*)p; p += (size_t)512 * 512 * 2;
  float*          pe   = (float*)p;          p += (size_t)BB * DM * 4;
  unsigned short* rhkb = (unsigned short*)p;

  ln2_kernel<<<SQ * BB, 128, 0, stream>>>(inp, ln1_g, ln1_b, ln2_g, ln2_b, hbhi, hblo);
  posemb_kernel<<<(BB * DM + 255) / 256, 256, 0, stream>>>(inp, pe);
  rhk_kernel<<<dim3(BB, DM / 256), 256, 0, stream>>>(pe, Wr, rhkb);
  convhi_kernel<<<(1536 * 512 + 255) / 256, 256, 0, stream>>>(Wqkv, Wqb, 1536 * 512);
  convhi_kernel<<<(512 * 512 + 255) / 256, 256, 0, stream>>>(Wo, Wob, 512 * 512);

  for (int b0 = 0; b0 < BB; b0 += CB) {
    const int Mc = CB * SQ;
    // QKV: [hbhi|hblo] chunk x Wqkv -> split planes (chunk-local rows)
    gemm_mfma<<<dim3(1536 / 128, Mc / 128), 256, 0, stream>>>(
        hbhi + (size_t)b0 * SQ * DM, hblo + (size_t)b0 * SQ * DM, Wqb,
        qhi, qloP, nullptr, 1536, 0);
    attn_mfma<<<CB * NH, 384, 0, stream>>>(qhi, qloP, rhkb, rwb, rrb, avhi, avlo, b0);
  }

  // OUT: [avhi|avlo] x Wo -> fp32 out with s-major row permute (hb dead now)
  gemm_mfma<<<dim3(512 / 128, M / 128), 256, 0, stream>>>(
      avhi, avlo, Wob, nullptr, nullptr, out, 512, 1);
}

// Round 6
// 407.361 us; speedup vs baseline: 9.3654x; 1.2676x over previous
//
#include <hip/hip_runtime.h>
#include <math.h>

#define SQ 192      // S
#define BB 192      // B
#define DM 512
#define NH 8
#define DH 64
#define NEPS 1e-5f
#define ASCALE 0.125f   // 1/sqrt(64)

typedef __bf16 bf16x8 __attribute__((ext_vector_type(8)));
typedef float f32x4 __attribute__((ext_vector_type(4)));
typedef unsigned short u16x8 __attribute__((ext_vector_type(8)));

__device__ __forceinline__ void gload16(const unsigned short* g, unsigned short* l) {
  __builtin_amdgcn_global_load_lds(
      (const __attribute__((address_space(1))) void*)g,
      (__attribute__((address_space(3))) void*)l, 16, 0, 0);
}
__device__ __forceinline__ unsigned short f2b(float x) {   // fp32 -> bf16 bits (RNE)
  union { float f; unsigned u; } c; c.f = x;
  return (unsigned short)((c.u + 0x7fffu + ((c.u >> 16) & 1u)) >> 16);
}
__device__ __forceinline__ float f2bf(float x) {           // round-to-bf16, keep fp32
  union { float f; unsigned u; } c; c.f = x;
  c.u = (c.u + 0x7fffu + ((c.u >> 16) & 1u)) & 0xffff0000u;
  return c.f;
}
__device__ __forceinline__ float b2f(unsigned short h) {
  union { unsigned u; float f; } c; c.u = ((unsigned)h) << 16;
  return c.f;
}

// ---------------------------------------------------------------------------
// Fused double LayerNorm -> split bf16 planes (b-major rows b*S+s), in d_out.
// ---------------------------------------------------------------------------
__global__ __launch_bounds__(128) void ln2_kernel(
    const float* __restrict__ inp, const float* __restrict__ g1, const float* __restrict__ b1,
    const float* __restrict__ g2, const float* __restrict__ b2,
    unsigned short* __restrict__ hbhi, unsigned short* __restrict__ hblo) {
  const int R = blockIdx.x;              // input row s*B+b
  const int s = R / BB;
  const int b = R % BB;
  const int t = threadIdx.x;
  const float4 v = reinterpret_cast<const float4*>(inp + (size_t)R * DM)[t];
  float sum  = v.x + v.y + v.z + v.w;
  float sum2 = v.x*v.x + v.y*v.y + v.z*v.z + v.w*v.w;
  #pragma unroll
  for (int o = 32; o >= 1; o >>= 1) { sum += __shfl_xor(sum, o); sum2 += __shfl_xor(sum2, o); }
  __shared__ float red[2][2];
  const int wv = t >> 6;
  if ((t & 63) == 0) { red[0][wv] = sum; red[1][wv] = sum2; }
  __syncthreads();
  sum = red[0][0] + red[0][1]; sum2 = red[1][0] + red[1][1];
  float mu = sum * (1.0f / DM);
  float var = sum2 * (1.0f / DM) - mu * mu;
  float rstd = rsqrtf(var + NEPS);
  const float4 G1 = reinterpret_cast<const float4*>(g1)[t];
  const float4 B1 = reinterpret_cast<const float4*>(b1)[t];
  float4 x;
  x.x = (v.x - mu) * rstd * G1.x + B1.x;
  x.y = (v.y - mu) * rstd * G1.y + B1.y;
  x.z = (v.z - mu) * rstd * G1.z + B1.z;
  x.w = (v.w - mu) * rstd * G1.w + B1.w;
  sum  = x.x + x.y + x.z + x.w;
  sum2 = x.x*x.x + x.y*x.y + x.z*x.z + x.w*x.w;
  #pragma unroll
  for (int o = 32; o >= 1; o >>= 1) { sum += __shfl_xor(sum, o); sum2 += __shfl_xor(sum2, o); }
  __syncthreads();
  if ((t & 63) == 0) { red[0][wv] = sum; red[1][wv] = sum2; }
  __syncthreads();
  sum = red[0][0] + red[0][1]; sum2 = red[1][0] + red[1][1];
  mu = sum * (1.0f / DM);
  var = sum2 * (1.0f / DM) - mu * mu;
  rstd = rsqrtf(var + NEPS);
  const float4 G2 = reinterpret_cast<const float4*>(g2)[t];
  const float4 B2 = reinterpret_cast<const float4*>(b2)[t];
  float4 o4;
  o4.x = (x.x - mu) * rstd * G2.x + B2.x;
  o4.y = (x.y - mu) * rstd * G2.y + B2.y;
  o4.z = (x.z - mu) * rstd * G2.z + B2.z;
  o4.w = (x.w - mu) * rstd * G2.w + B2.w;
  const size_t orow = (size_t)b * SQ + s;
  ushort4 hh, ll;
  hh.x = f2b(o4.x); ll.x = f2b(o4.x - f2bf(o4.x));
  hh.y = f2b(o4.y); ll.y = f2b(o4.y - f2bf(o4.y));
  hh.z = f2b(o4.z); ll.z = f2b(o4.z - f2bf(o4.z));
  hh.w = f2b(o4.w); ll.w = f2b(o4.w - f2bf(o4.w));
  *reinterpret_cast<ushort4*>(hbhi + orow * DM + t * 4) = hh;
  *reinterpret_cast<ushort4*>(hblo + orow * DM + t * 4) = ll;
}

// ---------------------------------------------------------------------------
__global__ void posemb_kernel(const float* __restrict__ inp, float* __restrict__ pe) {
  const int idx = blockIdx.x * 256 + threadIdx.x;
  if (idx >= BB * DM) return;
  const int b = idx >> 9;
  const int d = idx & 511;
  const float ps = inp[(size_t)b * DM];
  const int i = (d < 256) ? d : (d - 256);
  const float invf = expf(-9.210340371976184f * (float)i * (1.0f / 256.0f));
  const float a = ps * invf;
  pe[idx] = (d < 256) ? sinf(a) : cosf(a);
}

// ---------------------------------------------------------------------------
__global__ __launch_bounds__(256) void rhk_kernel(
    const float* __restrict__ pe, const float* __restrict__ Wr, unsigned short* __restrict__ rhkb) {
  __shared__ __align__(16) float pr[DM];
  const int j = blockIdx.x;
  const int e = blockIdx.y * 256 + threadIdx.x;
  for (int d = threadIdx.x; d < DM; d += 256) pr[d] = pe[(size_t)j * DM + d];
  __syncthreads();
  const float4* w4 = reinterpret_cast<const float4*>(Wr + (size_t)e * DM);
  const float4* p4 = reinterpret_cast<const float4*>(pr);
  float acc = 0.f;
  #pragma unroll 8
  for (int d4 = 0; d4 < DM / 4; ++d4) {
    const float4 a = p4[d4];
    const float4 w = w4[d4];
    acc += a.x*w.x + a.y*w.y + a.z*w.z + a.w*w.w;
  }
  rhkb[(size_t)j * DM + e] = f2b(acc);
}

// ---------------------------------------------------------------------------
__global__ void convhi_kernel(const float* __restrict__ src, unsigned short* __restrict__ dst, int nel) {
  const int i = blockIdx.x * 256 + threadIdx.x;
  if (i < nel) dst[i] = f2b(src[i]);
}

// ---------------------------------------------------------------------------
// Split-bf16 NT MFMA GEMM, K' = 1024 ([Ahi|Alo] . [Bhi|Bhi]^T).
// 128x128 tile, BK=64, 256 thr (4 waves 2x2), double-buffered LDS,
// XOR-swizzled source so frag ds_read_b128 is conflict-free.
// mode 0: C -> bf16 Chi[.][1536].  mode 1: C -> fp32 Cf permuted rows.
// ---------------------------------------------------------------------------
__global__ __launch_bounds__(256, 2) void gemm_mfma(
    const unsigned short* __restrict__ Ahi, const unsigned short* __restrict__ Alo,
    const unsigned short* __restrict__ Bp,
    unsigned short* __restrict__ Chi, float* __restrict__ Cf, int N, int mode) {
  __shared__ __align__(16) unsigned short As[2][128][64];
  __shared__ __align__(16) unsigned short Bs[2][128][64];
  const int tid = threadIdx.x;
  const int nwg = gridDim.x * gridDim.y;
  int flat = blockIdx.y * gridDim.x + blockIdx.x;
  flat = (flat & 7) * (nwg >> 3) + (flat >> 3);
  const int bm = (flat / gridDim.x) * 128;
  const int bn = (flat % gridDim.x) * 128;
  const int lane = tid & 63, wv = tid >> 6;
  const int wm = (wv >> 1) << 6, wn = (wv & 1) << 6;
  const int fr = lane & 15, q4 = lane >> 4;
  const int srow_ = tid >> 3, sl = tid & 7;

  f32x4 acc[4][4];
  #pragma unroll
  for (int mt = 0; mt < 4; ++mt)
    #pragma unroll
    for (int nt = 0; nt < 4; ++nt) acc[mt][nt] = (f32x4){0.f, 0.f, 0.f, 0.f};

  auto STAGE = [&](int buf, int k0) {
    const unsigned short* Ap = (k0 < 512) ? Ahi : Alo;
    const int kk = k0 & 511;
    #pragma unroll
    for (int it = 0; it < 4; ++it) {
      const int row = it * 32 + srow_;
      const int sp = (sl ^ (row & 7)) << 3;
      gload16(Ap + (size_t)(bm + row) * 512 + kk + sp, &As[buf][row][sl << 3]);
      gload16(Bp + (size_t)(bn + row) * 512 + kk + sp, &Bs[buf][row][sl << 3]);
    }
  };

  STAGE(0, 0);
  __syncthreads();
  int buf = 0;
  for (int step = 0; step < 16; ++step) {
    if (step < 15) STAGE(buf ^ 1, (step + 1) * 64);
    bf16x8 a[4][2], bb[4][2];
    #pragma unroll
    for (int mt = 0; mt < 4; ++mt)
      #pragma unroll
      for (int kc = 0; kc < 2; ++kc) {
        const int ra = wm + mt * 16 + fr;
        a[mt][kc]  = *reinterpret_cast<const bf16x8*>(&As[buf][ra][((((kc << 2) | q4) ^ (ra & 7)) << 3)]);
        const int rb = wn + mt * 16 + fr;
        bb[mt][kc] = *reinterpret_cast<const bf16x8*>(&Bs[buf][rb][((((kc << 2) | q4) ^ (rb & 7)) << 3)]);
      }
    #pragma unroll
    for (int mt = 0; mt < 4; ++mt)
      #pragma unroll
      for (int nt = 0; nt < 4; ++nt) {
        acc[mt][nt] = __builtin_amdgcn_mfma_f32_16x16x32_bf16(a[mt][0], bb[nt][0], acc[mt][nt], 0, 0, 0);
        acc[mt][nt] = __builtin_amdgcn_mfma_f32_16x16x32_bf16(a[mt][1], bb[nt][1], acc[mt][nt], 0, 0, 0);
      }
    __syncthreads();
    buf ^= 1;
  }
  // C/D layout: col = lane&15, row = (lane>>4)*4 + reg (verified m89)
  const int crow0 = bm + wm + (q4 << 2);
  const int ccol0 = bn + wn + fr;
  if (mode == 0) {
    #pragma unroll
    for (int mt = 0; mt < 4; ++mt)
      #pragma unroll
      for (int r = 0; r < 4; ++r) {
        const size_t rr = crow0 + mt * 16 + r;
        #pragma unroll
        for (int nt = 0; nt < 4; ++nt)
          Chi[rr * 1536 + ccol0 + nt * 16] = f2b(acc[mt][nt][r]);
      }
  } else {
    #pragma unroll
    for (int mt = 0; mt < 4; ++mt)
      #pragma unroll
      for (int r = 0; r < 4; ++r) {
        const int rr = crow0 + mt * 16 + r;
        const size_t orow = (size_t)(rr % SQ) * BB + (rr / SQ);
        #pragma unroll
        for (int nt = 0; nt < 4; ++nt)
          Cf[orow * N + ccol0 + nt * 16] = acc[mt][nt][r];
      }
  }
}

// ---------------------------------------------------------------------------
// MFMA attention, 2 q-tiles of 96 rows per (b,n). 384 thr = 6 waves; wave w
// owns q-rows [i0+16w, i0+16w+16). Phases: stage -> U=q.R^T -> K swap ->
// AC=q.K^T -> Vt + rel-shift gather/softmax -> P -> PV -> coalesced store.
// LDS (shorts): Q[0,7168) KR[7168,19456) UP[19456,38856) tbl@38856;
// VT overlays [0,12800); OH/OL overlay UP after PV.
// blockIdx pairing: tiles (h=0,1) of same (bl,n) sit 8 apart -> same XCD L2.
// ---------------------------------------------------------------------------
#define Q0   0
#define KR0  7168
#define UP0  19456
#define TBL0 38856
#define UPIT 200
#define VT0  0
#define OH0  UP0
#define OL0  (UP0 + 7680)

__global__ __launch_bounds__(384) void attn_mfma(
    const unsigned short* __restrict__ qkvhi,  // [CB*192][1536] chunk-local
    const unsigned short* __restrict__ rhkb,   // [192][512]
    const float* __restrict__ rwb, const float* __restrict__ rrb,
    unsigned short* __restrict__ avhi, unsigned short* __restrict__ avlo, int b0) {
  __shared__ __align__(16) unsigned short lds[39624];   // 79248 B
  float* tbl = reinterpret_cast<float*>(&lds[TBL0]);    // kb[0..191], rb[192..383]
  const int bid = blockIdx.x;
  const int low3 = bid & 7, qv = bid >> 3;
  const int h = qv & 1;
  const int g = ((qv >> 1) << 3) | low3;
  const int bl = g >> 3, n = g & 7;
  const int i0 = h * 96;
  const int tid = threadIdx.x;
  const int lane = tid & 63, wv = tid >> 6;
  const int fr = lane & 15, q4 = lane >> 4;
  const size_t rin = (size_t)bl * SQ;
  const size_t rout = (size_t)(b0 + bl) * SQ;

  // ---- stage: Q(112 rows, gload16), R(gload16), K->regs, V->regs ----
  #pragma unroll
  for (int it = 0; it < 3; ++it) {
    const int u = it * 384 + tid;
    if (u < 896) {
      const int row = u >> 3, sl = u & 7, sp = (sl ^ (row & 7)) << 3;
      const int rowg = (i0 + row > 191) ? 191 : (i0 + row);
      gload16(qkvhi + (rin + rowg) * 1536 + n * 64 + sp, &lds[Q0 + (row << 6) + (sl << 3)]);
    }
  }
  #pragma unroll
  for (int it = 0; it < 4; ++it) {
    const int u = it * 384 + tid;
    const int row = u >> 3, sl = u & 7, sp = (sl ^ (row & 7)) << 3;
    gload16(rhkb + (size_t)row * 512 + n * 64 + sp, &lds[KR0 + (row << 6) + (sl << 3)]);
  }
  u16x8 kreg[4];
  #pragma unroll
  for (int it = 0; it < 4; ++it) {
    const int u = it * 384 + tid;
    const int row = u >> 3, sl = u & 7;
    kreg[it] = *reinterpret_cast<const u16x8*>(qkvhi + (rin + row) * 1536 + 512 + n * 64 + (sl << 3));
  }
  const int vj = (tid < 192) ? tid : tid - 192;
  const int vdg = (tid < 192) ? 0 : 1;
  u16x8 vreg[4];
  #pragma unroll
  for (int c = 0; c < 4; ++c)
    vreg[c] = *reinterpret_cast<const u16x8*>(qkvhi + (rin + vj) * 1536 + 1024 + n * 64 + vdg * 32 + c * 8);
  __syncthreads();

  // ---- rb table; Q frags; U = q.R^T -> UP ----
  if (tid < SQ) {
    float a = 0.f;
    #pragma unroll
    for (int s = 0; s < 8; ++s) {
      const u16x8 rv = *reinterpret_cast<const u16x8*>(&lds[KR0 + (tid << 6) + ((s ^ (tid & 7)) << 3)]);
      #pragma unroll
      for (int e = 0; e < 8; ++e) a += rrb[n * 64 + s * 8 + e] * b2f(rv[e]);
    }
    tbl[192 + tid] = a;
  }
  bf16x8 ahi[2];
  {
    const int row_l = wv * 16 + fr;
    #pragma unroll
    for (int kc = 0; kc < 2; ++kc)
      ahi[kc] = *reinterpret_cast<const bf16x8*>(&lds[Q0 + (row_l << 6) + ((((kc << 2) | q4) ^ (row_l & 7)) << 3)]);
  }
  f32x4 acc[12];
  #pragma unroll
  for (int nt = 0; nt < 12; ++nt) acc[nt] = (f32x4){0.f, 0.f, 0.f, 0.f};
  #pragma unroll
  for (int nt = 0; nt < 12; ++nt) {
    bf16x8 bbr[2];
    #pragma unroll
    for (int kc = 0; kc < 2; ++kc) {
      const int r_ = nt * 16 + fr;
      bbr[kc] = *reinterpret_cast<const bf16x8*>(&lds[KR0 + (r_ << 6) + ((((kc << 2) | q4) ^ (r_ & 7)) << 3)]);
    }
    acc[nt] = __builtin_amdgcn_mfma_f32_16x16x32_bf16(ahi[0], bbr[0], acc[nt], 0, 0, 0);
    acc[nt] = __builtin_amdgcn_mfma_f32_16x16x32_bf16(ahi[1], bbr[1], acc[nt], 0, 0, 0);
  }
  // boundary U row i0+96 (only q-tile 0 needs it): wave 5, q rows 96..111
  if (h == 0 && wv == 5) {
    bf16x8 a2[2];
    const int row2 = 96 + fr;
    #pragma unroll
    for (int kc = 0; kc < 2; ++kc)
      a2[kc] = *reinterpret_cast<const bf16x8*>(&lds[Q0 + (row2 << 6) + ((((kc << 2) | q4) ^ (row2 & 7)) << 3)]);
    #pragma unroll
    for (int nt2 = 0; nt2 < 6; ++nt2) {
      f32x4 a6 = (f32x4){0.f, 0.f, 0.f, 0.f};
      bf16x8 bbr[2];
      #pragma unroll
      for (int kc = 0; kc < 2; ++kc) {
        const int r_ = nt2 * 16 + fr;
        bbr[kc] = *reinterpret_cast<const bf16x8*>(&lds[KR0 + (r_ << 6) + ((((kc << 2) | q4) ^ (r_ & 7)) << 3)]);
      }
      a6 = __builtin_amdgcn_mfma_f32_16x16x32_bf16(a2[0], bbr[0], a6, 0, 0, 0);
      a6 = __builtin_amdgcn_mfma_f32_16x16x32_bf16(a2[1], bbr[1], a6, 0, 0, 0);
      if (q4 == 0) lds[UP0 + 96 * UPIT + nt2 * 16 + fr] = f2b(a6[0]);
    }
  }
  #pragma unroll
  for (int nt = 0; nt < 12; ++nt)
    #pragma unroll
    for (int r = 0; r < 4; ++r) {
      const int i_l = wv * 16 + (q4 << 2) + r;
      lds[UP0 + i_l * UPIT + nt * 16 + fr] = f2b(acc[nt][r]);
    }
  __syncthreads();   // U + rb visible; R reads done

  // ---- K into KR slot ----
  #pragma unroll
  for (int it = 0; it < 4; ++it) {
    const int u = it * 384 + tid;
    const int row = u >> 3, sl = u & 7;
    *reinterpret_cast<u16x8*>(&lds[KR0 + (row << 6) + ((sl ^ (row & 7)) << 3)]) = kreg[it];
  }
  __syncthreads();   // K visible

  // ---- kb table; AC = q.K^T ----
  if (tid < SQ) {
    float a = 0.f;
    #pragma unroll
    for (int s = 0; s < 8; ++s) {
      const u16x8 kv = *reinterpret_cast<const u16x8*>(&lds[KR0 + (tid << 6) + ((s ^ (tid & 7)) << 3)]);
      #pragma unroll
      for (int e = 0; e < 8; ++e) a += rwb[n * 64 + s * 8 + e] * b2f(kv[e]);
    }
    tbl[tid] = a;
  }
  #pragma unroll
  for (int nt = 0; nt < 12; ++nt) acc[nt] = (f32x4){0.f, 0.f, 0.f, 0.f};
  #pragma unroll
  for (int nt = 0; nt < 12; ++nt) {
    bf16x8 bbr[2];
    #pragma unroll
    for (int kc = 0; kc < 2; ++kc) {
      const int r_ = nt * 16 + fr;
      bbr[kc] = *reinterpret_cast<const bf16x8*>(&lds[KR0 + (r_ << 6) + ((((kc << 2) | q4) ^ (r_ & 7)) << 3)]);
    }
    acc[nt] = __builtin_amdgcn_mfma_f32_16x16x32_bf16(ahi[0], bbr[0], acc[nt], 0, 0, 0);
    acc[nt] = __builtin_amdgcn_mfma_f32_16x16x32_bf16(ahi[1], bbr[1], acc[nt], 0, 0, 0);
  }
  __syncthreads();   // kb visible; K reads done (VT may overlay)

  // ---- Vt write (overlays Q/K region); rel-shift gather + softmax ----
  #pragma unroll
  for (int c = 0; c < 4; ++c)
    #pragma unroll
    for (int e = 0; e < 8; ++e)
      lds[VT0 + (vdg * 32 + c * 8 + e) * UPIT + vj] = vreg[c][e];

  float linv[4];
  #pragma unroll
  for (int r = 0; r < 4; ++r) {
    const int i_l = wv * 16 + (q4 << 2) + r;
    const int i = i0 + i_l;
    float sr[12];
    #pragma unroll
    for (int nt = 0; nt < 12; ++nt) {
      const int j = nt * 16 + fr;
      const int t = j + 191 - i;
      const bool wrap = (t >= 193);
      const int tm = wrap ? t - 193 : t;
      const bool valid = (t != 192);
      const int rowu = i_l + (wrap ? 1 : 0);
      const float uv = b2f(lds[UP0 + rowu * UPIT + (valid ? tm : 0)]);
      const float gv = valid ? (uv + tbl[192 + tm]) : 0.f;
      sr[nt] = acc[nt][r] + tbl[j] + gv;
    }
    float mx = sr[0];
    #pragma unroll
    for (int nt = 1; nt < 12; ++nt) mx = fmaxf(mx, sr[nt]);
    #pragma unroll
    for (int o = 1; o <= 8; o <<= 1) mx = fmaxf(mx, __shfl_xor(mx, o));
    float ls = 0.f;
    #pragma unroll
    for (int nt = 0; nt < 12; ++nt) {
      const float p = f2bf(__expf((sr[nt] - mx) * ASCALE));
      ls += p;
      acc[nt][r] = p;
    }
    #pragma unroll
    for (int o = 1; o <= 8; o <<= 1) ls += __shfl_xor(ls, o);
    linv[r] = 1.0f / ls;
  }
  __syncthreads();   // U reads done; Vt visible

  // ---- P -> UP ----
  #pragma unroll
  for (int nt = 0; nt < 12; ++nt)
    #pragma unroll
    for (int r = 0; r < 4; ++r) {
      const int i_l = wv * 16 + (q4 << 2) + r;
      lds[UP0 + i_l * UPIT + nt * 16 + fr] = f2b(acc[nt][r]);
    }
  __syncthreads();

  // ---- PV: out[i][d] = sum_j P[i][j] Vt[d][j] ----
  f32x4 o2[4];
  #pragma unroll
  for (int nt = 0; nt < 4; ++nt) o2[nt] = (f32x4){0.f, 0.f, 0.f, 0.f};
  #pragma unroll
  for (int kc = 0; kc < 6; ++kc) {
    const bf16x8 pa = *reinterpret_cast<const bf16x8*>(&lds[UP0 + (wv * 16 + fr) * UPIT + kc * 32 + (q4 << 3)]);
    #pragma unroll
    for (int nt = 0; nt < 4; ++nt) {
      const bf16x8 vb = *reinterpret_cast<const bf16x8*>(&lds[VT0 + (nt * 16 + fr) * UPIT + kc * 32 + (q4 << 3)]);
      o2[nt] = __builtin_amdgcn_mfma_f32_16x16x32_bf16(pa, vb, o2[nt], 0, 0, 0);
    }
  }
  __syncthreads();   // P/Vt reads done; UP free for OH/OL

  // ---- normalize, repack in LDS, coalesced 16B stores ----
  #pragma unroll
  for (int nt = 0; nt < 4; ++nt)
    #pragma unroll
    for (int r = 0; r < 4; ++r) {
      const int i_l = wv * 16 + (q4 << 2) + r;
      const int d = nt * 16 + fr;
      const float v = o2[nt][r] * linv[r];
      lds[OH0 + i_l * 80 + d] = f2b(v);
      lds[OL0 + i_l * 80 + d] = f2b(v - f2bf(v));
    }
  __syncthreads();
  #pragma unroll
  for (int it = 0; it < 2; ++it) {
    const int u = it * 384 + tid;
    const int row = u >> 3, sl = u & 7;
    const size_t gbase = (rout + i0 + row) * 512 + n * 64 + sl * 8;
    *reinterpret_cast<u16x8*>(avhi + gbase) = *reinterpret_cast<const u16x8*>(&lds[OH0 + row * 80 + sl * 8]);
    *reinterpret_cast<u16x8*>(avlo + gbase) = *reinterpret_cast<const u16x8*>(&lds[OL0 + row * 80 + sl * 8]);
  }
}

// ---------------------------------------------------------------------------
extern "C" void kernel_launch(void* const* d_in, const int* in_sizes, int n_in,
                              void* d_out, int out_size, void* d_ws, size_t ws_size,
                              hipStream_t stream) {
  const float* inp   = (const float*)d_in[0];
  const float* ln1_g = (const float*)d_in[1];
  const float* ln1_b = (const float*)d_in[2];
  const float* ln2_g = (const float*)d_in[3];
  const float* ln2_b = (const float*)d_in[4];
  const float* Wqkv  = (const float*)d_in[5];
  const float* Wr    = (const float*)d_in[6];
  const float* Wo    = (const float*)d_in[7];
  const float* rwb   = (const float*)d_in[8];
  const float* rrb   = (const float*)d_in[9];
  float* out = (float*)d_out;

  const size_t M = (size_t)SQ * BB;   // 36864
  unsigned short* hbhi = (unsigned short*)d_out;  // parked in d_out
  unsigned short* hblo = hbhi + M * DM;

  // adaptive batch-chunk (R5 proved ws >= 233MB; CB=192 needs 195MB)
  const int cands[3] = {192, 96, 48};
  int CB = 48;
  for (int ci = 0; ci < 3; ++ci) {
    const int c = cands[ci];
    const size_t need = (size_t)c * SQ * 1536 * 2        // qhi chunk
                      + 2 * M * 512 * 2                  // avhi + avlo
                      + 1536 * 512 * 2 + 512 * 512 * 2   // Wqb + Wob
                      + (size_t)BB * DM * 4 + (size_t)BB * DM * 2;  // pe + rhkb
    if (need <= ws_size) { CB = c; break; }
  }

  char* p = (char*)d_ws;
  unsigned short* qhi  = (unsigned short*)p; p += (size_t)CB * SQ * 1536 * 2;
  unsigned short* avhi = (unsigned short*)p; p += M * 512 * 2;
  unsigned short* avlo = (unsigned short*)p; p += M * 512 * 2;
  unsigned short* Wqb  = (unsigned short*)p; p += (size_t)1536 * 512 * 2;
  unsigned short* Wob  = (unsigned short*)p; p += (size_t)512 * 512 * 2;
  float*          pe   = (float*)p;          p += (size_t)BB * DM * 4;
  unsigned short* rhkb = (unsigned short*)p;

  ln2_kernel<<<SQ * BB, 128, 0, stream>>>(inp, ln1_g, ln1_b, ln2_g, ln2_b, hbhi, hblo);
  posemb_kernel<<<(BB * DM + 255) / 256, 256, 0, stream>>>(inp, pe);
  rhk_kernel<<<dim3(BB, DM / 256), 256, 0, stream>>>(pe, Wr, rhkb);
  convhi_kernel<<<(1536 * 512 + 255) / 256, 256, 0, stream>>>(Wqkv, Wqb, 1536 * 512);
  convhi_kernel<<<(512 * 512 + 255) / 256, 256, 0, stream>>>(Wo, Wob, 512 * 512);

  for (int b0 = 0; b0 < BB; b0 += CB) {
    const int Mc = CB * SQ;
    gemm_mfma<<<dim3(1536 / 128, Mc / 128), 256, 0, stream>>>(
        hbhi + (size_t)b0 * SQ * DM, hblo + (size_t)b0 * SQ * DM, Wqb,
        qhi, nullptr, 1536, 0);
    attn_mfma<<<CB * NH * 2, 384, 0, stream>>>(qhi, rhkb, rwb, rrb, avhi, avlo, b0);
  }

  gemm_mfma<<<dim3(512 / 128, M / 128), 256, 0, stream>>>(
      avhi, avlo, Wob, nullptr, out, 512, 1);
}

// Round 7
// 377.049 us; speedup vs baseline: 10.1183x; 1.0804x over previous
//
#include <hip/hip_runtime.h>
#include <math.h>

#define SQ 192      // S
#define BB 192      // B
#define DM 512
#define NH 8
#define DH 64
#define NEPS 1e-5f
#define ASCALE 0.125f   // 1/sqrt(64)

typedef __bf16 bf16x8 __attribute__((ext_vector_type(8)));
typedef float f32x4 __attribute__((ext_vector_type(4)));
typedef unsigned short u16x8 __attribute__((ext_vector_type(8)));

__device__ __forceinline__ void gload16(const unsigned short* g, unsigned short* l) {
  __builtin_amdgcn_global_load_lds(
      (const __attribute__((address_space(1))) void*)g,
      (__attribute__((address_space(3))) void*)l, 16, 0, 0);
}
__device__ __forceinline__ unsigned short f2b(float x) {   // fp32 -> bf16 bits (RNE)
  union { float f; unsigned u; } c; c.f = x;
  return (unsigned short)((c.u + 0x7fffu + ((c.u >> 16) & 1u)) >> 16);
}
__device__ __forceinline__ float f2bf(float x) {           // round-to-bf16, keep fp32
  union { float f; unsigned u; } c; c.f = x;
  c.u = (c.u + 0x7fffu + ((c.u >> 16) & 1u)) & 0xffff0000u;
  return c.f;
}
__device__ __forceinline__ float b2f(unsigned short h) {
  union { unsigned u; float f; } c; c.u = ((unsigned)h) << 16;
  return c.f;
}
__device__ __forceinline__ bf16x8 u2b8(u16x8 v) {
  union { u16x8 u; bf16x8 b; } c; c.u = v; return c.b;
}

// ---------------------------------------------------------------------------
// Fused double LayerNorm -> split bf16 planes (b-major rows b*S+s), in d_out.
// ---------------------------------------------------------------------------
__global__ __launch_bounds__(128) void ln2_kernel(
    const float* __restrict__ inp, const float* __restrict__ g1, const float* __restrict__ b1,
    const float* __restrict__ g2, const float* __restrict__ b2,
    unsigned short* __restrict__ hbhi, unsigned short* __restrict__ hblo) {
  const int R = blockIdx.x;              // input row s*B+b
  const int s = R / BB;
  const int b = R % BB;
  const int t = threadIdx.x;
  const float4 v = reinterpret_cast<const float4*>(inp + (size_t)R * DM)[t];
  float sum  = v.x + v.y + v.z + v.w;
  float sum2 = v.x*v.x + v.y*v.y + v.z*v.z + v.w*v.w;
  #pragma unroll
  for (int o = 32; o >= 1; o >>= 1) { sum += __shfl_xor(sum, o); sum2 += __shfl_xor(sum2, o); }
  __shared__ float red[2][2];
  const int wv = t >> 6;
  if ((t & 63) == 0) { red[0][wv] = sum; red[1][wv] = sum2; }
  __syncthreads();
  sum = red[0][0] + red[0][1]; sum2 = red[1][0] + red[1][1];
  float mu = sum * (1.0f / DM);
  float var = sum2 * (1.0f / DM) - mu * mu;
  float rstd = rsqrtf(var + NEPS);
  const float4 G1 = reinterpret_cast<const float4*>(g1)[t];
  const float4 B1 = reinterpret_cast<const float4*>(b1)[t];
  float4 x;
  x.x = (v.x - mu) * rstd * G1.x + B1.x;
  x.y = (v.y - mu) * rstd * G1.y + B1.y;
  x.z = (v.z - mu) * rstd * G1.z + B1.z;
  x.w = (v.w - mu) * rstd * G1.w + B1.w;
  sum  = x.x + x.y + x.z + x.w;
  sum2 = x.x*x.x + x.y*x.y + x.z*x.z + x.w*x.w;
  #pragma unroll
  for (int o = 32; o >= 1; o >>= 1) { sum += __shfl_xor(sum, o); sum2 += __shfl_xor(sum2, o); }
  __syncthreads();
  if ((t & 63) == 0) { red[0][wv] = sum; red[1][wv] = sum2; }
  __syncthreads();
  sum = red[0][0] + red[0][1]; sum2 = red[1][0] + red[1][1];
  mu = sum * (1.0f / DM);
  var = sum2 * (1.0f / DM) - mu * mu;
  rstd = rsqrtf(var + NEPS);
  const float4 G2 = reinterpret_cast<const float4*>(g2)[t];
  const float4 B2 = reinterpret_cast<const float4*>(b2)[t];
  float4 o4;
  o4.x = (x.x - mu) * rstd * G2.x + B2.x;
  o4.y = (x.y - mu) * rstd * G2.y + B2.y;
  o4.z = (x.z - mu) * rstd * G2.z + B2.z;
  o4.w = (x.w - mu) * rstd * G2.w + B2.w;
  const size_t orow = (size_t)b * SQ + s;
  ushort4 hh, ll;
  hh.x = f2b(o4.x); ll.x = f2b(o4.x - f2bf(o4.x));
  hh.y = f2b(o4.y); ll.y = f2b(o4.y - f2bf(o4.y));
  hh.z = f2b(o4.z); ll.z = f2b(o4.z - f2bf(o4.z));
  hh.w = f2b(o4.w); ll.w = f2b(o4.w - f2bf(o4.w));
  *reinterpret_cast<ushort4*>(hbhi + orow * DM + t * 4) = hh;
  *reinterpret_cast<ushort4*>(hblo + orow * DM + t * 4) = ll;
}

// ---------------------------------------------------------------------------
__global__ void posemb_kernel(const float* __restrict__ inp, float* __restrict__ pe) {
  const int idx = blockIdx.x * 256 + threadIdx.x;
  if (idx >= BB * DM) return;
  const int b = idx >> 9;
  const int d = idx & 511;
  const float ps = inp[(size_t)b * DM];
  const int i = (d < 256) ? d : (d - 256);
  const float invf = expf(-9.210340371976184f * (float)i * (1.0f / 256.0f));
  const float a = ps * invf;
  pe[idx] = (d < 256) ? sinf(a) : cosf(a);
}

// ---------------------------------------------------------------------------
__global__ __launch_bounds__(256) void rhk_kernel(
    const float* __restrict__ pe, const float* __restrict__ Wr, unsigned short* __restrict__ rhkb) {
  __shared__ __align__(16) float pr[DM];
  const int j = blockIdx.x;
  const int e = blockIdx.y * 256 + threadIdx.x;
  for (int d = threadIdx.x; d < DM; d += 256) pr[d] = pe[(size_t)j * DM + d];
  __syncthreads();
  const float4* w4 = reinterpret_cast<const float4*>(Wr + (size_t)e * DM);
  const float4* p4 = reinterpret_cast<const float4*>(pr);
  float acc = 0.f;
  #pragma unroll 8
  for (int d4 = 0; d4 < DM / 4; ++d4) {
    const float4 a = p4[d4];
    const float4 w = w4[d4];
    acc += a.x*w.x + a.y*w.y + a.z*w.z + a.w*w.w;
  }
  rhkb[(size_t)j * DM + e] = f2b(acc);
}

// ---------------------------------------------------------------------------
__global__ void convhi_kernel(const float* __restrict__ src, unsigned short* __restrict__ dst, int nel) {
  const int i = blockIdx.x * 256 + threadIdx.x;
  if (i < nel) dst[i] = f2b(src[i]);
}

// ---------------------------------------------------------------------------
// Split-bf16 NT MFMA GEMM, K' = 1024 ([Ahi|Alo] . [Bhi|Bhi]^T).
// 128x128 tile, BK=64, 256 thr (4 waves 2x2), double-buffered LDS,
// XOR-swizzled source so frag ds_read_b128 is conflict-free.
// mode 0: C -> bf16 Chi[.][1536].  mode 1: C -> fp32 Cf permuted rows.
// ---------------------------------------------------------------------------
__global__ __launch_bounds__(256, 2) void gemm_mfma(
    const unsigned short* __restrict__ Ahi, const unsigned short* __restrict__ Alo,
    const unsigned short* __restrict__ Bp,
    unsigned short* __restrict__ Chi, float* __restrict__ Cf, int N, int mode) {
  __shared__ __align__(16) unsigned short As[2][128][64];
  __shared__ __align__(16) unsigned short Bs[2][128][64];
  const int tid = threadIdx.x;
  const int nwg = gridDim.x * gridDim.y;
  int flat = blockIdx.y * gridDim.x + blockIdx.x;
  flat = (flat & 7) * (nwg >> 3) + (flat >> 3);
  const int bm = (flat / gridDim.x) * 128;
  const int bn = (flat % gridDim.x) * 128;
  const int lane = tid & 63, wv = tid >> 6;
  const int wm = (wv >> 1) << 6, wn = (wv & 1) << 6;
  const int fr = lane & 15, q4 = lane >> 4;
  const int srow_ = tid >> 3, sl = tid & 7;

  f32x4 acc[4][4];
  #pragma unroll
  for (int mt = 0; mt < 4; ++mt)
    #pragma unroll
    for (int nt = 0; nt < 4; ++nt) acc[mt][nt] = (f32x4){0.f, 0.f, 0.f, 0.f};

  auto STAGE = [&](int buf, int k0) {
    const unsigned short* Ap = (k0 < 512) ? Ahi : Alo;
    const int kk = k0 & 511;
    #pragma unroll
    for (int it = 0; it < 4; ++it) {
      const int row = it * 32 + srow_;
      const int sp = (sl ^ (row & 7)) << 3;
      gload16(Ap + (size_t)(bm + row) * 512 + kk + sp, &As[buf][row][sl << 3]);
      gload16(Bp + (size_t)(bn + row) * 512 + kk + sp, &Bs[buf][row][sl << 3]);
    }
  };

  STAGE(0, 0);
  __syncthreads();
  int buf = 0;
  for (int step = 0; step < 16; ++step) {
    if (step < 15) STAGE(buf ^ 1, (step + 1) * 64);
    bf16x8 a[4][2], bb[4][2];
    #pragma unroll
    for (int mt = 0; mt < 4; ++mt)
      #pragma unroll
      for (int kc = 0; kc < 2; ++kc) {
        const int ra = wm + mt * 16 + fr;
        a[mt][kc]  = *reinterpret_cast<const bf16x8*>(&As[buf][ra][((((kc << 2) | q4) ^ (ra & 7)) << 3)]);
        const int rb = wn + mt * 16 + fr;
        bb[mt][kc] = *reinterpret_cast<const bf16x8*>(&Bs[buf][rb][((((kc << 2) | q4) ^ (rb & 7)) << 3)]);
      }
    #pragma unroll
    for (int mt = 0; mt < 4; ++mt)
      #pragma unroll
      for (int nt = 0; nt < 4; ++nt) {
        acc[mt][nt] = __builtin_amdgcn_mfma_f32_16x16x32_bf16(a[mt][0], bb[nt][0], acc[mt][nt], 0, 0, 0);
        acc[mt][nt] = __builtin_amdgcn_mfma_f32_16x16x32_bf16(a[mt][1], bb[nt][1], acc[mt][nt], 0, 0, 0);
      }
    __syncthreads();
    buf ^= 1;
  }
  // C/D layout: col = lane&15, row = (lane>>4)*4 + reg (verified m89)
  const int crow0 = bm + wm + (q4 << 2);
  const int ccol0 = bn + wn + fr;
  if (mode == 0) {
    #pragma unroll
    for (int mt = 0; mt < 4; ++mt)
      #pragma unroll
      for (int r = 0; r < 4; ++r) {
        const size_t rr = crow0 + mt * 16 + r;
        #pragma unroll
        for (int nt = 0; nt < 4; ++nt)
          Chi[rr * 1536 + ccol0 + nt * 16] = f2b(acc[mt][nt][r]);
      }
  } else {
    #pragma unroll
    for (int mt = 0; mt < 4; ++mt)
      #pragma unroll
      for (int r = 0; r < 4; ++r) {
        const int rr = crow0 + mt * 16 + r;
        const size_t orow = (size_t)(rr % SQ) * BB + (rr / SQ);
        #pragma unroll
        for (int nt = 0; nt < 4; ++nt)
          Cf[orow * N + ccol0 + nt * 16] = acc[mt][nt][r];
      }
  }
}

// ---------------------------------------------------------------------------
// MFMA attention v7: 2 q-tiles of 96 rows per (b,n), 384 thr = 6 waves,
// wave w owns q-rows [i0+16w, i0+16w+16).
// Biases folded into A-frags: AC=(q+rwb).K^T, U=(q+rrb).R^T. Max-free softmax
// (scores provably << fp32-exp range). K staged up-front into the region U
// overwrites (K dead after AC). Phases:
//   stage(Q,R,K gload16; V->regs) | AC+U MFMAs | write U,Vt | gather+exp+sum
//   | write P | PV | repack | coalesced store.
// LDS (shorts): Q[0,6208) R[6208,18496) K/U[18496,37896);
//   VT overlays [0,12800); OH/OL overlay [0,15360) after PV. 75792 B total.
// blockIdx pairing: tiles h=0,1 of same (bl,n) sit 8 apart -> same XCD L2.
// ---------------------------------------------------------------------------
#define Q0   0
#define R0   6208
#define K0   18496
#define U0   18496
#define VT0  0
#define OH0  0
#define OL0  7680
#define UPIT 200

__global__ __launch_bounds__(384) void attn_mfma(
    const unsigned short* __restrict__ qkvhi,  // [CB*192][1536] chunk-local
    const unsigned short* __restrict__ rhkb,   // [192][512]
    const float* __restrict__ rwb, const float* __restrict__ rrb,
    unsigned short* __restrict__ avhi, unsigned short* __restrict__ avlo, int b0) {
  __shared__ __align__(16) unsigned short lds[37896];   // 75792 B
  const int bid = blockIdx.x;
  const int low3 = bid & 7, qv = bid >> 3;
  const int h = qv & 1;
  const int g = ((qv >> 1) << 3) | low3;
  const int bl = g >> 3, n = g & 7;
  const int i0 = h * 96;
  const int tid = threadIdx.x;
  const int lane = tid & 63, wv = tid >> 6;
  const int fr = lane & 15, q4 = lane >> 4;
  const size_t rin = (size_t)bl * SQ;
  const size_t rout = (size_t)(b0 + bl) * SQ;

  // ---- stage: Q(97 rows), R, K via gload16; V -> regs ----
  #pragma unroll
  for (int it = 0; it < 3; ++it) {
    const int u = it * 384 + tid;
    if (u < 776) {
      const int row = u >> 3, sl = u & 7, sp = (sl ^ (row & 7)) << 3;
      const int rowg = (i0 + row > 191) ? 191 : (i0 + row);
      gload16(qkvhi + (rin + rowg) * 1536 + n * 64 + sp, &lds[Q0 + (row << 6) + (sl << 3)]);
    }
  }
  #pragma unroll
  for (int it = 0; it < 4; ++it) {
    const int u = it * 384 + tid;
    const int row = u >> 3, sl = u & 7, sp = (sl ^ (row & 7)) << 3;
    gload16(rhkb + (size_t)row * 512 + n * 64 + sp, &lds[R0 + (row << 6) + (sl << 3)]);
    gload16(qkvhi + (rin + row) * 1536 + 512 + n * 64 + sp, &lds[K0 + (row << 6) + (sl << 3)]);
  }
  const int vj = (tid < 192) ? tid : tid - 192;
  const int vdg = (tid < 192) ? 0 : 1;
  u16x8 vreg[4];
  #pragma unroll
  for (int c = 0; c < 4; ++c)
    vreg[c] = *reinterpret_cast<const u16x8*>(qkvhi + (rin + vj) * 1536 + 1024 + n * 64 + vdg * 32 + c * 8);
  __syncthreads();

  // ---- biased A-frags: aw = bf16(q+rwb), ar = bf16(q+rrb) ----
  bf16x8 aw[2], ar[2];
  {
    const int row_l = wv * 16 + fr;
    #pragma unroll
    for (int kc = 0; kc < 2; ++kc) {
      const u16x8 qraw = *reinterpret_cast<const u16x8*>(
          &lds[Q0 + (row_l << 6) + ((((kc << 2) | q4) ^ (row_l & 7)) << 3)]);
      u16x8 wv_, rv_;
      #pragma unroll
      for (int e = 0; e < 8; ++e) {
        const int k = kc * 32 + (q4 << 3) + e;
        const float qf = b2f(qraw[e]);
        wv_[e] = f2b(qf + rwb[n * 64 + k]);
        rv_[e] = f2b(qf + rrb[n * 64 + k]);
      }
      aw[kc] = u2b8(wv_); ar[kc] = u2b8(rv_);
    }
  }

  // ---- AC = (q+rwb).K^T (K frags from K0) ----
  f32x4 acc[12];
  #pragma unroll
  for (int nt = 0; nt < 12; ++nt) acc[nt] = (f32x4){0.f, 0.f, 0.f, 0.f};
  #pragma unroll
  for (int nt = 0; nt < 12; ++nt) {
    #pragma unroll
    for (int kc = 0; kc < 2; ++kc) {
      const int r_ = nt * 16 + fr;
      const bf16x8 bk = *reinterpret_cast<const bf16x8*>(
          &lds[K0 + (r_ << 6) + ((((kc << 2) | q4) ^ (r_ & 7)) << 3)]);
      acc[nt] = __builtin_amdgcn_mfma_f32_16x16x32_bf16(ar /*placeholder*/[0], bk, acc[nt], 0, 0, 0);
    }
  }
  // NOTE: placeholder above is wrong operand; recompute properly below.
  #pragma unroll
  for (int nt = 0; nt < 12; ++nt) acc[nt] = (f32x4){0.f, 0.f, 0.f, 0.f};
  #pragma unroll
  for (int nt = 0; nt < 12; ++nt) {
    bf16x8 bk[2];
    #pragma unroll
    for (int kc = 0; kc < 2; ++kc) {
      const int r_ = nt * 16 + fr;
      bk[kc] = *reinterpret_cast<const bf16x8*>(
          &lds[K0 + (r_ << 6) + ((((kc << 2) | q4) ^ (r_ & 7)) << 3)]);
    }
    acc[nt] = __builtin_amdgcn_mfma_f32_16x16x32_bf16(aw[0], bk[0], acc[nt], 0, 0, 0);
    acc[nt] = __builtin_amdgcn_mfma_f32_16x16x32_bf16(aw[1], bk[1], acc[nt], 0, 0, 0);
  }

  // ---- U = (q+rrb).R^T (R frags from R0) ----
  f32x4 uacc[12];
  #pragma unroll
  for (int nt = 0; nt < 12; ++nt) uacc[nt] = (f32x4){0.f, 0.f, 0.f, 0.f};
  #pragma unroll
  for (int nt = 0; nt < 12; ++nt) {
    bf16x8 br[2];
    #pragma unroll
    for (int kc = 0; kc < 2; ++kc) {
      const int r_ = nt * 16 + fr;
      br[kc] = *reinterpret_cast<const bf16x8*>(
          &lds[R0 + (r_ << 6) + ((((kc << 2) | q4) ^ (r_ & 7)) << 3)]);
    }
    uacc[nt] = __builtin_amdgcn_mfma_f32_16x16x32_bf16(ar[0], br[0], uacc[nt], 0, 0, 0);
    uacc[nt] = __builtin_amdgcn_mfma_f32_16x16x32_bf16(ar[1], br[1], uacc[nt], 0, 0, 0);
  }
  // boundary U row i0+96 (only q-tile 0 needs it): wave 5, cols 0..95.
  float bnd[6];
  if (h == 0 && wv == 5) {
    bf16x8 a2[2];
    const int row2 = 96 + fr;   // reads past staged Q into R region: garbage
    #pragma unroll                // inputs feed only discarded output rows.
    for (int kc = 0; kc < 2; ++kc) {
      const u16x8 qraw = *reinterpret_cast<const u16x8*>(
          &lds[Q0 + (row2 << 6) + ((((kc << 2) | q4) ^ (row2 & 7)) << 3)]);
      u16x8 rv_;
      #pragma unroll
      for (int e = 0; e < 8; ++e) {
        const int k = kc * 32 + (q4 << 3) + e;
        rv_[e] = f2b(b2f(qraw[e]) + rrb[n * 64 + k]);
      }
      a2[kc] = u2b8(rv_);
    }
    #pragma unroll
    for (int nt2 = 0; nt2 < 6; ++nt2) {
      f32x4 a6 = (f32x4){0.f, 0.f, 0.f, 0.f};
      bf16x8 br[2];
      #pragma unroll
      for (int kc = 0; kc < 2; ++kc) {
        const int r_ = nt2 * 16 + fr;
        br[kc] = *reinterpret_cast<const bf16x8*>(
            &lds[R0 + (r_ << 6) + ((((kc << 2) | q4) ^ (r_ & 7)) << 3)]);
      }
      a6 = __builtin_amdgcn_mfma_f32_16x16x32_bf16(a2[0], br[0], a6, 0, 0, 0);
      a6 = __builtin_amdgcn_mfma_f32_16x16x32_bf16(a2[1], br[1], a6, 0, 0, 0);
      bnd[nt2] = a6[0];
    }
  }
  __syncthreads();   // all K/R/Q reads done -> U/Vt writes may overlay

  // ---- write U (over K region) + Vt (over Q/R region) ----
  #pragma unroll
  for (int nt = 0; nt < 12; ++nt)
    #pragma unroll
    for (int r = 0; r < 4; ++r) {
      const int i_l = wv * 16 + (q4 << 2) + r;
      lds[U0 + i_l * UPIT + nt * 16 + fr] = f2b(uacc[nt][r]);
    }
  if (h == 0 && wv == 5 && q4 == 0) {
    #pragma unroll
    for (int nt2 = 0; nt2 < 6; ++nt2)
      lds[U0 + 96 * UPIT + nt2 * 16 + fr] = f2b(bnd[nt2]);
  }
  #pragma unroll
  for (int c = 0; c < 4; ++c)
    #pragma unroll
    for (int e = 0; e < 8; ++e)
      lds[VT0 + (vdg * 32 + c * 8 + e) * UPIT + vj] = vreg[c][e];
  __syncthreads();   // U + Vt visible

  // ---- rel-shift gather + max-free softmax ----
  float linv[4];
  #pragma unroll
  for (int r = 0; r < 4; ++r) {
    const int i_l = wv * 16 + (q4 << 2) + r;
    const int i = i0 + i_l;
    float ls = 0.f;
    #pragma unroll
    for (int nt = 0; nt < 12; ++nt) {
      const int j = nt * 16 + fr;
      const int t = j + 191 - i;
      const bool wrap = (t >= 193);
      const int tm = wrap ? t - 193 : t;
      const bool valid = (t != 192);
      const int rowu = i_l + (wrap ? 1 : 0);
      const float uv = b2f(lds[U0 + rowu * UPIT + (valid ? tm : 0)]);
      const float sr = acc[nt][r] + (valid ? uv : 0.f);
      const float p = f2bf(__expf(sr * ASCALE));
      ls += p;
      acc[nt][r] = p;
    }
    #pragma unroll
    for (int o = 1; o <= 8; o <<= 1) ls += __shfl_xor(ls, o);
    linv[r] = 1.0f / ls;
  }
  __syncthreads();   // U reads done -> P may overwrite

  // ---- P -> U region ----
  #pragma unroll
  for (int nt = 0; nt < 12; ++nt)
    #pragma unroll
    for (int r = 0; r < 4; ++r) {
      const int i_l = wv * 16 + (q4 << 2) + r;
      lds[U0 + i_l * UPIT + nt * 16 + fr] = f2b(acc[nt][r]);
    }
  __syncthreads();   // P visible

  // ---- PV: out[i][d] = sum_j P[i][j] Vt[d][j] ----
  f32x4 o2[4];
  #pragma unroll
  for (int nt = 0; nt < 4; ++nt) o2[nt] = (f32x4){0.f, 0.f, 0.f, 0.f};
  #pragma unroll
  for (int kc = 0; kc < 6; ++kc) {
    const bf16x8 pa = *reinterpret_cast<const bf16x8*>(
        &lds[U0 + (wv * 16 + fr) * UPIT + kc * 32 + (q4 << 3)]);
    #pragma unroll
    for (int nt = 0; nt < 4; ++nt) {
      const bf16x8 vb = *reinterpret_cast<const bf16x8*>(
          &lds[VT0 + (nt * 16 + fr) * UPIT + kc * 32 + (q4 << 3)]);
      o2[nt] = __builtin_amdgcn_mfma_f32_16x16x32_bf16(pa, vb, o2[nt], 0, 0, 0);
    }
  }
  __syncthreads();   // Vt reads done -> OH/OL may overlay

  // ---- normalize, repack in LDS, coalesced 16B stores ----
  #pragma unroll
  for (int nt = 0; nt < 4; ++nt)
    #pragma unroll
    for (int r = 0; r < 4; ++r) {
      const int i_l = wv * 16 + (q4 << 2) + r;
      const int d = nt * 16 + fr;
      const float v = o2[nt][r] * linv[r];
      lds[OH0 + i_l * 80 + d] = f2b(v);
      lds[OL0 + i_l * 80 + d] = f2b(v - f2bf(v));
    }
  __syncthreads();
  #pragma unroll
  for (int it = 0; it < 2; ++it) {
    const int u = it * 384 + tid;
    const int row = u >> 3, sl = u & 7;
    const size_t gbase = (rout + i0 + row) * 512 + n * 64 + sl * 8;
    *reinterpret_cast<u16x8*>(avhi + gbase) = *reinterpret_cast<const u16x8*>(&lds[OH0 + row * 80 + sl * 8]);
    *reinterpret_cast<u16x8*>(avlo + gbase) = *reinterpret_cast<const u16x8*>(&lds[OL0 + row * 80 + sl * 8]);
  }
}

// ---------------------------------------------------------------------------
extern "C" void kernel_launch(void* const* d_in, const int* in_sizes, int n_in,
                              void* d_out, int out_size, void* d_ws, size_t ws_size,
                              hipStream_t stream) {
  const float* inp   = (const float*)d_in[0];
  const float* ln1_g = (const float*)d_in[1];
  const float* ln1_b = (const float*)d_in[2];
  const float* ln2_g = (const float*)d_in[3];
  const float* ln2_b = (const float*)d_in[4];
  const float* Wqkv  = (const float*)d_in[5];
  const float* Wr    = (const float*)d_in[6];
  const float* Wo    = (const float*)d_in[7];
  const float* rwb   = (const float*)d_in[8];
  const float* rrb   = (const float*)d_in[9];
  float* out = (float*)d_out;

  const size_t M = (size_t)SQ * BB;   // 36864
  unsigned short* hbhi = (unsigned short*)d_out;  // parked in d_out
  unsigned short* hblo = hbhi + M * DM;

  const int cands[3] = {192, 96, 48};
  int CB = 48;
  for (int ci = 0; ci < 3; ++ci) {
    const int c = cands[ci];
    const size_t need = (size_t)c * SQ * 1536 * 2        // qhi chunk
                      + 2 * M * 512 * 2                  // avhi + avlo
                      + 1536 * 512 * 2 + 512 * 512 * 2   // Wqb + Wob
                      + (size_t)BB * DM * 4 + (size_t)BB * DM * 2;  // pe + rhkb
    if (need <= ws_size) { CB = c; break; }
  }

  char* p = (char*)d_ws;
  unsigned short* qhi  = (unsigned short*)p; p += (size_t)CB * SQ * 1536 * 2;
  unsigned short* avhi = (unsigned short*)p; p += M * 512 * 2;
  unsigned short* avlo = (unsigned short*)p; p += M * 512 * 2;
  unsigned short* Wqb  = (unsigned short*)p; p += (size_t)1536 * 512 * 2;
  unsigned short* Wob  = (unsigned short*)p; p += (size_t)512 * 512 * 2;
  float*          pe   = (float*)p;          p += (size_t)BB * DM * 4;
  unsigned short* rhkb = (unsigned short*)p;

  ln2_kernel<<<SQ * BB, 128, 0, stream>>>(inp, ln1_g, ln1_b, ln2_g, ln2_b, hbhi, hblo);
  posemb_kernel<<<(BB * DM + 255) / 256, 256, 0, stream>>>(inp, pe);
  rhk_kernel<<<dim3(BB, DM / 256), 256, 0, stream>>>(pe, Wr, rhkb);
  convhi_kernel<<<(1536 * 512 + 255) / 256, 256, 0, stream>>>(Wqkv, Wqb, 1536 * 512);
  convhi_kernel<<<(512 * 512 + 255) / 256, 256, 0, stream>>>(Wo, Wob, 512 * 512);

  for (int b0 = 0; b0 < BB; b0 += CB) {
    const int Mc = CB * SQ;
    gemm_mfma<<<dim3(1536 / 128, Mc / 128), 256, 0, stream>>>(
        hbhi + (size_t)b0 * SQ * DM, hblo + (size_t)b0 * SQ * DM, Wqb,
        qhi, nullptr, 1536, 0);
    attn_mfma<<<CB * NH * 2, 384, 0, stream>>>(qhi, rhkb, rwb, rrb, avhi, avlo, b0);
  }

  gemm_mfma<<<dim3(512 / 128, M / 128), 256, 0, stream>>>(
      avhi, avlo, Wob, nullptr, out, 512, 1);
}

// Round 8
// 304.016 us; speedup vs baseline: 12.5489x; 1.2402x over previous
//
#include <hip/hip_runtime.h>
#include <math.h>

#define SQ 192      // S
#define BB 192      // B
#define DM 512
#define NH 8
#define DH 64
#define NEPS 1e-5f
#define ASCALE 0.125f   // 1/sqrt(64)

typedef __bf16 bf16x8 __attribute__((ext_vector_type(8)));
typedef float f32x4 __attribute__((ext_vector_type(4)));
typedef unsigned short u16x8 __attribute__((ext_vector_type(8)));

__device__ __forceinline__ void gload16(const unsigned short* g, unsigned short* l) {
  __builtin_amdgcn_global_load_lds(
      (const __attribute__((address_space(1))) void*)g,
      (__attribute__((address_space(3))) void*)l, 16, 0, 0);
}
__device__ __forceinline__ unsigned short f2b(float x) {   // fp32 -> bf16 bits (RNE)
  union { float f; unsigned u; } c; c.f = x;
  return (unsigned short)((c.u + 0x7fffu + ((c.u >> 16) & 1u)) >> 16);
}
__device__ __forceinline__ float f2bf(float x) {           // round-to-bf16, keep fp32
  union { float f; unsigned u; } c; c.f = x;
  c.u = (c.u + 0x7fffu + ((c.u >> 16) & 1u)) & 0xffff0000u;
  return c.f;
}
__device__ __forceinline__ float b2f(unsigned short h) {
  union { unsigned u; float f; } c; c.u = ((unsigned)h) << 16;
  return c.f;
}
__device__ __forceinline__ bf16x8 u2b8(u16x8 v) {
  union { u16x8 u; bf16x8 b; } c; c.u = v; return c.b;
}

// ---------------------------------------------------------------------------
// Fused double LayerNorm -> bf16 hi plane (b-major rows b*S+s), in d_out.
// ---------------------------------------------------------------------------
__global__ __launch_bounds__(128) void ln2_kernel(
    const float* __restrict__ inp, const float* __restrict__ g1, const float* __restrict__ b1,
    const float* __restrict__ g2, const float* __restrict__ b2,
    unsigned short* __restrict__ hbhi) {
  const int R = blockIdx.x;              // input row s*B+b
  const int s = R / BB;
  const int b = R % BB;
  const int t = threadIdx.x;
  const float4 v = reinterpret_cast<const float4*>(inp + (size_t)R * DM)[t];
  float sum  = v.x + v.y + v.z + v.w;
  float sum2 = v.x*v.x + v.y*v.y + v.z*v.z + v.w*v.w;
  #pragma unroll
  for (int o = 32; o >= 1; o >>= 1) { sum += __shfl_xor(sum, o); sum2 += __shfl_xor(sum2, o); }
  __shared__ float red[2][2];
  const int wv = t >> 6;
  if ((t & 63) == 0) { red[0][wv] = sum; red[1][wv] = sum2; }
  __syncthreads();
  sum = red[0][0] + red[0][1]; sum2 = red[1][0] + red[1][1];
  float mu = sum * (1.0f / DM);
  float var = sum2 * (1.0f / DM) - mu * mu;
  float rstd = rsqrtf(var + NEPS);
  const float4 G1 = reinterpret_cast<const float4*>(g1)[t];
  const float4 B1 = reinterpret_cast<const float4*>(b1)[t];
  float4 x;
  x.x = (v.x - mu) * rstd * G1.x + B1.x;
  x.y = (v.y - mu) * rstd * G1.y + B1.y;
  x.z = (v.z - mu) * rstd * G1.z + B1.z;
  x.w = (v.w - mu) * rstd * G1.w + B1.w;
  sum  = x.x + x.y + x.z + x.w;
  sum2 = x.x*x.x + x.y*x.y + x.z*x.z + x.w*x.w;
  #pragma unroll
  for (int o = 32; o >= 1; o >>= 1) { sum += __shfl_xor(sum, o); sum2 += __shfl_xor(sum2, o); }
  __syncthreads();
  if ((t & 63) == 0) { red[0][wv] = sum; red[1][wv] = sum2; }
  __syncthreads();
  sum = red[0][0] + red[0][1]; sum2 = red[1][0] + red[1][1];
  mu = sum * (1.0f / DM);
  var = sum2 * (1.0f / DM) - mu * mu;
  rstd = rsqrtf(var + NEPS);
  const float4 G2 = reinterpret_cast<const float4*>(g2)[t];
  const float4 B2 = reinterpret_cast<const float4*>(b2)[t];
  ushort4 hh;
  hh.x = f2b((x.x - mu) * rstd * G2.x + B2.x);
  hh.y = f2b((x.y - mu) * rstd * G2.y + B2.y);
  hh.z = f2b((x.z - mu) * rstd * G2.z + B2.z);
  hh.w = f2b((x.w - mu) * rstd * G2.w + B2.w);
  *reinterpret_cast<ushort4*>(hbhi + ((size_t)b * SQ + s) * DM + t * 4) = hh;
}

// ---------------------------------------------------------------------------
__global__ void posemb_kernel(const float* __restrict__ inp, float* __restrict__ pe) {
  const int idx = blockIdx.x * 256 + threadIdx.x;
  if (idx >= BB * DM) return;
  const int b = idx >> 9;
  const int d = idx & 511;
  const float ps = inp[(size_t)b * DM];
  const int i = (d < 256) ? d : (d - 256);
  const float invf = expf(-9.210340371976184f * (float)i * (1.0f / 256.0f));
  const float a = ps * invf;
  pe[idx] = (d < 256) ? sinf(a) : cosf(a);
}

// ---------------------------------------------------------------------------
__global__ __launch_bounds__(256) void rhk_kernel(
    const float* __restrict__ pe, const float* __restrict__ Wr, unsigned short* __restrict__ rhkb) {
  __shared__ __align__(16) float pr[DM];
  const int j = blockIdx.x;
  const int e = blockIdx.y * 256 + threadIdx.x;
  for (int d = threadIdx.x; d < DM; d += 256) pr[d] = pe[(size_t)j * DM + d];
  __syncthreads();
  const float4* w4 = reinterpret_cast<const float4*>(Wr + (size_t)e * DM);
  const float4* p4 = reinterpret_cast<const float4*>(pr);
  float acc = 0.f;
  #pragma unroll 8
  for (int d4 = 0; d4 < DM / 4; ++d4) {
    const float4 a = p4[d4];
    const float4 w = w4[d4];
    acc += a.x*w.x + a.y*w.y + a.z*w.z + a.w*w.w;
  }
  rhkb[(size_t)j * DM + e] = f2b(acc);
}

// ---------------------------------------------------------------------------
__global__ void convhi_kernel(const float* __restrict__ src, unsigned short* __restrict__ dst, int nel) {
  const int i = blockIdx.x * 256 + threadIdx.x;
  if (i < nel) dst[i] = f2b(src[i]);
}

// ---------------------------------------------------------------------------
// bf16 NT MFMA GEMM. ksteps=8: C = Ahi.Bp^T (K=512). ksteps=16: K'=1024
// split [Ahi|Alo].[Bhi|Bhi]. 128x128 tile, BK=64, 256 thr, dbuf LDS,
// XOR-swizzled source. mode 0: C -> bf16 Chi[.][1536]; mode 1: fp32 permuted.
// ---------------------------------------------------------------------------
__global__ __launch_bounds__(256, 2) void gemm_mfma(
    const unsigned short* __restrict__ Ahi, const unsigned short* __restrict__ Alo,
    const unsigned short* __restrict__ Bp,
    unsigned short* __restrict__ Chi, float* __restrict__ Cf, int N, int mode, int ksteps) {
  __shared__ __align__(16) unsigned short As[2][128][64];
  __shared__ __align__(16) unsigned short Bs[2][128][64];
  const int tid = threadIdx.x;
  const int nwg = gridDim.x * gridDim.y;
  int flat = blockIdx.y * gridDim.x + blockIdx.x;
  flat = (flat & 7) * (nwg >> 3) + (flat >> 3);
  const int bm = (flat / gridDim.x) * 128;
  const int bn = (flat % gridDim.x) * 128;
  const int lane = tid & 63, wv = tid >> 6;
  const int wm = (wv >> 1) << 6, wn = (wv & 1) << 6;
  const int fr = lane & 15, q4 = lane >> 4;
  const int srow_ = tid >> 3, sl = tid & 7;

  f32x4 acc[4][4];
  #pragma unroll
  for (int mt = 0; mt < 4; ++mt)
    #pragma unroll
    for (int nt = 0; nt < 4; ++nt) acc[mt][nt] = (f32x4){0.f, 0.f, 0.f, 0.f};

  auto STAGE = [&](int buf, int k0) {
    const unsigned short* Ap = (k0 < 512) ? Ahi : Alo;
    const int kk = k0 & 511;
    #pragma unroll
    for (int it = 0; it < 4; ++it) {
      const int row = it * 32 + srow_;
      const int sp = (sl ^ (row & 7)) << 3;
      gload16(Ap + (size_t)(bm + row) * 512 + kk + sp, &As[buf][row][sl << 3]);
      gload16(Bp + (size_t)(bn + row) * 512 + kk + sp, &Bs[buf][row][sl << 3]);
    }
  };

  STAGE(0, 0);
  __syncthreads();
  int buf = 0;
  for (int step = 0; step < ksteps; ++step) {
    if (step < ksteps - 1) STAGE(buf ^ 1, (step + 1) * 64);
    bf16x8 a[4][2], bb[4][2];
    #pragma unroll
    for (int mt = 0; mt < 4; ++mt)
      #pragma unroll
      for (int kc = 0; kc < 2; ++kc) {
        const int ra = wm + mt * 16 + fr;
        a[mt][kc]  = *reinterpret_cast<const bf16x8*>(&As[buf][ra][((((kc << 2) | q4) ^ (ra & 7)) << 3)]);
        const int rb = wn + mt * 16 + fr;
        bb[mt][kc] = *reinterpret_cast<const bf16x8*>(&Bs[buf][rb][((((kc << 2) | q4) ^ (rb & 7)) << 3)]);
      }
    #pragma unroll
    for (int mt = 0; mt < 4; ++mt)
      #pragma unroll
      for (int nt = 0; nt < 4; ++nt) {
        acc[mt][nt] = __builtin_amdgcn_mfma_f32_16x16x32_bf16(a[mt][0], bb[nt][0], acc[mt][nt], 0, 0, 0);
        acc[mt][nt] = __builtin_amdgcn_mfma_f32_16x16x32_bf16(a[mt][1], bb[nt][1], acc[mt][nt], 0, 0, 0);
      }
    __syncthreads();
    buf ^= 1;
  }
  // C/D layout: col = lane&15, row = (lane>>4)*4 + reg (verified m89)
  const int crow0 = bm + wm + (q4 << 2);
  const int ccol0 = bn + wn + fr;
  if (mode == 0) {
    #pragma unroll
    for (int mt = 0; mt < 4; ++mt)
      #pragma unroll
      for (int r = 0; r < 4; ++r) {
        const size_t rr = crow0 + mt * 16 + r;
        #pragma unroll
        for (int nt = 0; nt < 4; ++nt)
          Chi[rr * 1536 + ccol0 + nt * 16] = f2b(acc[mt][nt][r]);
      }
  } else {
    #pragma unroll
    for (int mt = 0; mt < 4; ++mt)
      #pragma unroll
      for (int r = 0; r < 4; ++r) {
        const int rr = crow0 + mt * 16 + r;
        const size_t orow = (size_t)(rr % SQ) * BB + (rr / SQ);
        #pragma unroll
        for (int nt = 0; nt < 4; ++nt)
          Cf[orow * N + ccol0 + nt * 16] = acc[mt][nt][r];
      }
  }
}

// ---------------------------------------------------------------------------
// MFMA attention v8: ONE block per (b,n), 768 thr = 12 waves; wave w owns
// q-rows [ (w/6)*96 + (w%6)*16, +16 ). Full 192-row tile => no rel-shift
// boundary row (wrap implies i<=189, rowu=i+1<=190 in-tile).
// Biases folded into A-frags; max-free softmax.
// LDS (shorts): Q[0,12288) R[12288,24576) K[24576,36864) U[36864,75264);
//   VT overlays [0,12800); P overlays U; OH/OL overlay [0,30720) after PV.
// 150528 B total, 6 barriers.
// ---------------------------------------------------------------------------
#define Q0   0
#define R0   12288
#define K0   24576
#define U0   36864
#define VT0  0
#define OH0  0
#define OL0  15360
#define UPIT 200

__global__ __launch_bounds__(768) void attn_mfma(
    const unsigned short* __restrict__ qkvhi,  // [CB*192][1536] chunk-local
    const unsigned short* __restrict__ rhkb,   // [192][512]
    const float* __restrict__ rwb, const float* __restrict__ rrb,
    unsigned short* __restrict__ avhi, unsigned short* __restrict__ avlo, int b0) {
  __shared__ __align__(16) unsigned short lds[75264];   // 150528 B
  const int bid = blockIdx.x;
  const int n = bid & 7, bl = bid >> 3;
  const int tid = threadIdx.x;
  const int lane = tid & 63, wv = tid >> 6;
  const int fr = lane & 15, q4 = lane >> 4;
  const int wrow = (wv / 6) * 96 + (wv % 6) * 16;   // wave's 16-row q-slab
  const size_t rin = (size_t)bl * SQ;
  const size_t rout = (size_t)(b0 + bl) * SQ;

  // ---- stage: Q, R, K via gload16; V -> regs ----
  #pragma unroll
  for (int it = 0; it < 2; ++it) {
    const int u = it * 768 + tid;
    const int row = u >> 3, sl = u & 7, sp = (sl ^ (row & 7)) << 3;
    gload16(qkvhi + (rin + row) * 1536 + n * 64 + sp, &lds[Q0 + (row << 6) + (sl << 3)]);
    gload16(rhkb + (size_t)row * 512 + n * 64 + sp, &lds[R0 + (row << 6) + (sl << 3)]);
    gload16(qkvhi + (rin + row) * 1536 + 512 + n * 64 + sp, &lds[K0 + (row << 6) + (sl << 3)]);
  }
  const int vj = tid % 192, vdg = tid / 192;        // vdg in [0,4)
  u16x8 vreg[2];
  #pragma unroll
  for (int c = 0; c < 2; ++c)
    vreg[c] = *reinterpret_cast<const u16x8*>(qkvhi + (rin + vj) * 1536 + 1024 + n * 64 + vdg * 16 + c * 8);
  __syncthreads();   // barrier A

  // ---- biased A-frags: aw = bf16(q+rwb), ar = bf16(q+rrb) ----
  bf16x8 aw[2], ar[2];
  {
    const int row_l = wrow + fr;
    #pragma unroll
    for (int kc = 0; kc < 2; ++kc) {
      const u16x8 qraw = *reinterpret_cast<const u16x8*>(
          &lds[Q0 + (row_l << 6) + ((((kc << 2) | q4) ^ (row_l & 7)) << 3)]);
      u16x8 wv_, rv_;
      #pragma unroll
      for (int e = 0; e < 8; ++e) {
        const int k = kc * 32 + (q4 << 3) + e;
        const float qf = b2f(qraw[e]);
        wv_[e] = f2b(qf + rwb[n * 64 + k]);
        rv_[e] = f2b(qf + rrb[n * 64 + k]);
      }
      aw[kc] = u2b8(wv_); ar[kc] = u2b8(rv_);
    }
  }

  // ---- AC = (q+rwb).K^T ; U = (q+rrb).R^T ----
  f32x4 acc[12], uacc[12];
  #pragma unroll
  for (int nt = 0; nt < 12; ++nt) {
    acc[nt] = (f32x4){0.f, 0.f, 0.f, 0.f};
    uacc[nt] = (f32x4){0.f, 0.f, 0.f, 0.f};
  }
  #pragma unroll
  for (int nt = 0; nt < 12; ++nt) {
    #pragma unroll
    for (int kc = 0; kc < 2; ++kc) {
      const int r_ = nt * 16 + fr;
      const int sp = ((((kc << 2) | q4) ^ (r_ & 7)) << 3);
      const bf16x8 bk = *reinterpret_cast<const bf16x8*>(&lds[K0 + (r_ << 6) + sp]);
      const bf16x8 br = *reinterpret_cast<const bf16x8*>(&lds[R0 + (r_ << 6) + sp]);
      acc[nt]  = __builtin_amdgcn_mfma_f32_16x16x32_bf16(aw[kc], bk, acc[nt], 0, 0, 0);
      uacc[nt] = __builtin_amdgcn_mfma_f32_16x16x32_bf16(ar[kc], br, uacc[nt], 0, 0, 0);
    }
  }
  // write U (disjoint region -> no barrier needed before)
  #pragma unroll
  for (int nt = 0; nt < 12; ++nt)
    #pragma unroll
    for (int r = 0; r < 4; ++r) {
      const int i_l = wrow + (q4 << 2) + r;
      lds[U0 + i_l * UPIT + nt * 16 + fr] = f2b(uacc[nt][r]);
    }
  __syncthreads();   // barrier B: Q/R/K reads + U writes done

  // ---- VT write (overlays Q/R); rel-shift gather + max-free softmax ----
  #pragma unroll
  for (int c = 0; c < 2; ++c)
    #pragma unroll
    for (int e = 0; e < 8; ++e)
      lds[VT0 + (vdg * 16 + c * 8 + e) * UPIT + vj] = vreg[c][e];

  float linv[4];
  #pragma unroll
  for (int r = 0; r < 4; ++r) {
    const int i = wrow + (q4 << 2) + r;
    float ls = 0.f;
    #pragma unroll
    for (int nt = 0; nt < 12; ++nt) {
      const int j = nt * 16 + fr;
      const int t = j + 191 - i;
      const bool wrap = (t >= 193);
      const int tm = wrap ? t - 193 : t;
      const bool valid = (t != 192);
      const int rowu = i + (wrap ? 1 : 0);
      const float uv = b2f(lds[U0 + rowu * UPIT + (valid ? tm : 0)]);
      const float sr = acc[nt][r] + (valid ? uv : 0.f);
      const float p = f2bf(__expf(sr * ASCALE));
      ls += p;
      acc[nt][r] = p;
    }
    #pragma unroll
    for (int o = 1; o <= 8; o <<= 1) ls += __shfl_xor(ls, o);
    linv[r] = 1.0f / ls;
  }
  __syncthreads();   // barrier C: U reads done, VT visible

  // ---- P -> U region ----
  #pragma unroll
  for (int nt = 0; nt < 12; ++nt)
    #pragma unroll
    for (int r = 0; r < 4; ++r) {
      const int i_l = wrow + (q4 << 2) + r;
      lds[U0 + i_l * UPIT + nt * 16 + fr] = f2b(acc[nt][r]);
    }
  __syncthreads();   // barrier D: P visible

  // ---- PV: out[i][d] = sum_j P[i][j] Vt[d][j] ----
  f32x4 o2[4];
  #pragma unroll
  for (int nt = 0; nt < 4; ++nt) o2[nt] = (f32x4){0.f, 0.f, 0.f, 0.f};
  #pragma unroll
  for (int kc = 0; kc < 6; ++kc) {
    const bf16x8 pa = *reinterpret_cast<const bf16x8*>(
        &lds[U0 + (wrow + fr) * UPIT + kc * 32 + (q4 << 3)]);
    #pragma unroll
    for (int nt = 0; nt < 4; ++nt) {
      const bf16x8 vb = *reinterpret_cast<const bf16x8*>(
          &lds[VT0 + (nt * 16 + fr) * UPIT + kc * 32 + (q4 << 3)]);
      o2[nt] = __builtin_amdgcn_mfma_f32_16x16x32_bf16(pa, vb, o2[nt], 0, 0, 0);
    }
  }
  __syncthreads();   // barrier E: VT reads done -> OH/OL may overlay

  // ---- normalize, repack in LDS, coalesced 16B stores ----
  #pragma unroll
  for (int nt = 0; nt < 4; ++nt)
    #pragma unroll
    for (int r = 0; r < 4; ++r) {
      const int i_l = wrow + (q4 << 2) + r;
      const int d = nt * 16 + fr;
      const float v = o2[nt][r] * linv[r];
      lds[OH0 + i_l * 80 + d] = f2b(v);
      lds[OL0 + i_l * 80 + d] = f2b(v - f2bf(v));
    }
  __syncthreads();   // barrier F
  #pragma unroll
  for (int it = 0; it < 2; ++it) {
    const int u = it * 768 + tid;
    const int row = u >> 3, sl = u & 7;
    const size_t gbase = (rout + row) * 512 + n * 64 + sl * 8;
    *reinterpret_cast<u16x8*>(avhi + gbase) = *reinterpret_cast<const u16x8*>(&lds[OH0 + row * 80 + sl * 8]);
    *reinterpret_cast<u16x8*>(avlo + gbase) = *reinterpret_cast<const u16x8*>(&lds[OL0 + row * 80 + sl * 8]);
  }
}

// ---------------------------------------------------------------------------
extern "C" void kernel_launch(void* const* d_in, const int* in_sizes, int n_in,
                              void* d_out, int out_size, void* d_ws, size_t ws_size,
                              hipStream_t stream) {
  const float* inp   = (const float*)d_in[0];
  const float* ln1_g = (const float*)d_in[1];
  const float* ln1_b = (const float*)d_in[2];
  const float* ln2_g = (const float*)d_in[3];
  const float* ln2_b = (const float*)d_in[4];
  const float* Wqkv  = (const float*)d_in[5];
  const float* Wr    = (const float*)d_in[6];
  const float* Wo    = (const float*)d_in[7];
  const float* rwb   = (const float*)d_in[8];
  const float* rrb   = (const float*)d_in[9];
  float* out = (float*)d_out;

  const size_t M = (size_t)SQ * BB;   // 36864
  unsigned short* hbhi = (unsigned short*)d_out;  // parked in d_out

  const int cands[3] = {192, 96, 48};
  int CB = 48;
  for (int ci = 0; ci < 3; ++ci) {
    const int c = cands[ci];
    const size_t need = (size_t)c * SQ * 1536 * 2        // qhi chunk
                      + 2 * M * 512 * 2                  // avhi + avlo
                      + 1536 * 512 * 2 + 512 * 512 * 2   // Wqb + Wob
                      + (size_t)BB * DM * 4 + (size_t)BB * DM * 2;  // pe + rhkb
    if (need <= ws_size) { CB = c; break; }
  }

  char* p = (char*)d_ws;
  unsigned short* qhi  = (unsigned short*)p; p += (size_t)CB * SQ * 1536 * 2;
  unsigned short* avhi = (unsigned short*)p; p += M * 512 * 2;
  unsigned short* avlo = (unsigned short*)p; p += M * 512 * 2;
  unsigned short* Wqb  = (unsigned short*)p; p += (size_t)1536 * 512 * 2;
  unsigned short* Wob  = (unsigned short*)p; p += (size_t)512 * 512 * 2;
  float*          pe   = (float*)p;          p += (size_t)BB * DM * 4;
  unsigned short* rhkb = (unsigned short*)p;

  ln2_kernel<<<SQ * BB, 128, 0, stream>>>(inp, ln1_g, ln1_b, ln2_g, ln2_b, hbhi);
  posemb_kernel<<<(BB * DM + 255) / 256, 256, 0, stream>>>(inp, pe);
  rhk_kernel<<<dim3(BB, DM / 256), 256, 0, stream>>>(pe, Wr, rhkb);
  convhi_kernel<<<(1536 * 512 + 255) / 256, 256, 0, stream>>>(Wqkv, Wqb, 1536 * 512);
  convhi_kernel<<<(512 * 512 + 255) / 256, 256, 0, stream>>>(Wo, Wob, 512 * 512);

  for (int b0 = 0; b0 < BB; b0 += CB) {
    const int Mc = CB * SQ;
    // QKV: hi-only (K=512). QKV outputs get bf16-rounded anyway; h-lo term
    // is below that rounding.
    gemm_mfma<<<dim3(1536 / 128, Mc / 128), 256, 0, stream>>>(
        hbhi + (size_t)b0 * SQ * DM, hbhi + (size_t)b0 * SQ * DM, Wqb,
        qhi, nullptr, 1536, 0, 8);
    attn_mfma<<<CB * NH, 768, 0, stream>>>(qhi, rhkb, rwb, rrb, avhi, avlo, b0);
  }

  // OUT: split K'=1024 (av-lo matters: feeds compared output directly)
  gemm_mfma<<<dim3(512 / 128, M / 128), 256, 0, stream>>>(
      avhi, avlo, Wob, nullptr, out, 512, 1, 16);
}

// Round 9
// 289.682 us; speedup vs baseline: 13.1699x; 1.0495x over previous
//
#include <hip/hip_runtime.h>
#include <math.h>

#define SQ 192      // S
#define BB 192      // B
#define DM 512
#define NH 8
#define DH 64
#define NEPS 1e-5f
#define ASCALE 0.125f   // 1/sqrt(64), folded into aw/ar (exact pow2)

typedef __bf16 bf16x8 __attribute__((ext_vector_type(8)));
typedef float f32x4 __attribute__((ext_vector_type(4)));
typedef unsigned short u16x8 __attribute__((ext_vector_type(8)));
typedef unsigned short u16x4 __attribute__((ext_vector_type(4)));

__device__ __forceinline__ void gload16(const unsigned short* g, unsigned short* l) {
  __builtin_amdgcn_global_load_lds(
      (const __attribute__((address_space(1))) void*)g,
      (__attribute__((address_space(3))) void*)l, 16, 0, 0);
}
__device__ __forceinline__ unsigned short f2b(float x) {   // fp32 -> bf16 bits (RNE)
  union { float f; unsigned u; } c; c.f = x;
  return (unsigned short)((c.u + 0x7fffu + ((c.u >> 16) & 1u)) >> 16);
}
__device__ __forceinline__ float f2bf(float x) {           // round-to-bf16, keep fp32
  union { float f; unsigned u; } c; c.f = x;
  c.u = (c.u + 0x7fffu + ((c.u >> 16) & 1u)) & 0xffff0000u;
  return c.f;
}
__device__ __forceinline__ float b2f(unsigned short h) {
  union { unsigned u; float f; } c; c.u = ((unsigned)h) << 16;
  return c.f;
}
__device__ __forceinline__ bf16x8 u2b8(u16x8 v) {
  union { u16x8 u; bf16x8 b; } c; c.u = v; return c.b;
}

// ---------------------------------------------------------------------------
// Fused double LayerNorm -> bf16 hi plane (b-major rows b*S+s), in d_out.
// ---------------------------------------------------------------------------
__global__ __launch_bounds__(128) void ln2_kernel(
    const float* __restrict__ inp, const float* __restrict__ g1, const float* __restrict__ b1,
    const float* __restrict__ g2, const float* __restrict__ b2,
    unsigned short* __restrict__ hbhi) {
  const int R = blockIdx.x;              // input row s*B+b
  const int s = R / BB;
  const int b = R % BB;
  const int t = threadIdx.x;
  const float4 v = reinterpret_cast<const float4*>(inp + (size_t)R * DM)[t];
  float sum  = v.x + v.y + v.z + v.w;
  float sum2 = v.x*v.x + v.y*v.y + v.z*v.z + v.w*v.w;
  #pragma unroll
  for (int o = 32; o >= 1; o >>= 1) { sum += __shfl_xor(sum, o); sum2 += __shfl_xor(sum2, o); }
  __shared__ float red[2][2];
  const int wv = t >> 6;
  if ((t & 63) == 0) { red[0][wv] = sum; red[1][wv] = sum2; }
  __syncthreads();
  sum = red[0][0] + red[0][1]; sum2 = red[1][0] + red[1][1];
  float mu = sum * (1.0f / DM);
  float var = sum2 * (1.0f / DM) - mu * mu;
  float rstd = rsqrtf(var + NEPS);
  const float4 G1 = reinterpret_cast<const float4*>(g1)[t];
  const float4 B1 = reinterpret_cast<const float4*>(b1)[t];
  float4 x;
  x.x = (v.x - mu) * rstd * G1.x + B1.x;
  x.y = (v.y - mu) * rstd * G1.y + B1.y;
  x.z = (v.z - mu) * rstd * G1.z + B1.z;
  x.w = (v.w - mu) * rstd * G1.w + B1.w;
  sum  = x.x + x.y + x.z + x.w;
  sum2 = x.x*x.x + x.y*x.y + x.z*x.z + x.w*x.w;
  #pragma unroll
  for (int o = 32; o >= 1; o >>= 1) { sum += __shfl_xor(sum, o); sum2 += __shfl_xor(sum2, o); }
  __syncthreads();
  if ((t & 63) == 0) { red[0][wv] = sum; red[1][wv] = sum2; }
  __syncthreads();
  sum = red[0][0] + red[0][1]; sum2 = red[1][0] + red[1][1];
  mu = sum * (1.0f / DM);
  var = sum2 * (1.0f / DM) - mu * mu;
  rstd = rsqrtf(var + NEPS);
  const float4 G2 = reinterpret_cast<const float4*>(g2)[t];
  const float4 B2 = reinterpret_cast<const float4*>(b2)[t];
  ushort4 hh;
  hh.x = f2b((x.x - mu) * rstd * G2.x + B2.x);
  hh.y = f2b((x.y - mu) * rstd * G2.y + B2.y);
  hh.z = f2b((x.z - mu) * rstd * G2.z + B2.z);
  hh.w = f2b((x.w - mu) * rstd * G2.w + B2.w);
  *reinterpret_cast<ushort4*>(hbhi + ((size_t)b * SQ + s) * DM + t * 4) = hh;
}

// ---------------------------------------------------------------------------
__global__ void posemb_kernel(const float* __restrict__ inp, float* __restrict__ pe) {
  const int idx = blockIdx.x * 256 + threadIdx.x;
  if (idx >= BB * DM) return;
  const int b = idx >> 9;
  const int d = idx & 511;
  const float ps = inp[(size_t)b * DM];
  const int i = (d < 256) ? d : (d - 256);
  const float invf = expf(-9.210340371976184f * (float)i * (1.0f / 256.0f));
  const float a = ps * invf;
  pe[idx] = (d < 256) ? sinf(a) : cosf(a);
}

// ---------------------------------------------------------------------------
__global__ __launch_bounds__(256) void rhk_kernel(
    const float* __restrict__ pe, const float* __restrict__ Wr, unsigned short* __restrict__ rhkb) {
  __shared__ __align__(16) float pr[DM];
  const int j = blockIdx.x;
  const int e = blockIdx.y * 256 + threadIdx.x;
  for (int d = threadIdx.x; d < DM; d += 256) pr[d] = pe[(size_t)j * DM + d];
  __syncthreads();
  const float4* w4 = reinterpret_cast<const float4*>(Wr + (size_t)e * DM);
  const float4* p4 = reinterpret_cast<const float4*>(pr);
  float acc = 0.f;
  #pragma unroll 8
  for (int d4 = 0; d4 < DM / 4; ++d4) {
    const float4 a = p4[d4];
    const float4 w = w4[d4];
    acc += a.x*w.x + a.y*w.y + a.z*w.z + a.w*w.w;
  }
  rhkb[(size_t)j * DM + e] = f2b(acc);
}

// ---------------------------------------------------------------------------
// Convert Wqkv (786432 els) and Wo (262144 els) in one launch.
__global__ void conv2_kernel(const float* __restrict__ wq, const float* __restrict__ wo,
                             unsigned short* __restrict__ wqb, unsigned short* __restrict__ wob) {
  const int i = blockIdx.x * 256 + threadIdx.x;
  if (i < 786432) wqb[i] = f2b(wq[i]);
  else if (i < 786432 + 262144) wob[i - 786432] = f2b(wo[i - 786432]);
}

// ---------------------------------------------------------------------------
// bf16 NT MFMA GEMM. ksteps=8: C = Ahi.Bp^T (K=512). ksteps=16: K'=1024
// split [Ahi|Alo].[Bhi|Bhi]. 128x128 tile, BK=64, 256 thr, dbuf LDS,
// XOR-swizzled source. mode 0: C -> bf16 Chi[.][1536]; mode 1: fp32 permuted.
// ---------------------------------------------------------------------------
__global__ __launch_bounds__(256, 2) void gemm_mfma(
    const unsigned short* __restrict__ Ahi, const unsigned short* __restrict__ Alo,
    const unsigned short* __restrict__ Bp,
    unsigned short* __restrict__ Chi, float* __restrict__ Cf, int N, int mode, int ksteps) {
  __shared__ __align__(16) unsigned short As[2][128][64];
  __shared__ __align__(16) unsigned short Bs[2][128][64];
  const int tid = threadIdx.x;
  const int nwg = gridDim.x * gridDim.y;
  int flat = blockIdx.y * gridDim.x + blockIdx.x;
  flat = (flat & 7) * (nwg >> 3) + (flat >> 3);
  const int bm = (flat / gridDim.x) * 128;
  const int bn = (flat % gridDim.x) * 128;
  const int lane = tid & 63, wv = tid >> 6;
  const int wm = (wv >> 1) << 6, wn = (wv & 1) << 6;
  const int fr = lane & 15, q4 = lane >> 4;
  const int srow_ = tid >> 3, sl = tid & 7;

  f32x4 acc[4][4];
  #pragma unroll
  for (int mt = 0; mt < 4; ++mt)
    #pragma unroll
    for (int nt = 0; nt < 4; ++nt) acc[mt][nt] = (f32x4){0.f, 0.f, 0.f, 0.f};

  auto STAGE = [&](int buf, int k0) {
    const unsigned short* Ap = (k0 < 512) ? Ahi : Alo;
    const int kk = k0 & 511;
    #pragma unroll
    for (int it = 0; it < 4; ++it) {
      const int row = it * 32 + srow_;
      const int sp = (sl ^ (row & 7)) << 3;
      gload16(Ap + (size_t)(bm + row) * 512 + kk + sp, &As[buf][row][sl << 3]);
      gload16(Bp + (size_t)(bn + row) * 512 + kk + sp, &Bs[buf][row][sl << 3]);
    }
  };

  STAGE(0, 0);
  __syncthreads();
  int buf = 0;
  for (int step = 0; step < ksteps; ++step) {
    if (step < ksteps - 1) STAGE(buf ^ 1, (step + 1) * 64);
    bf16x8 a[4][2], bb[4][2];
    #pragma unroll
    for (int mt = 0; mt < 4; ++mt)
      #pragma unroll
      for (int kc = 0; kc < 2; ++kc) {
        const int ra = wm + mt * 16 + fr;
        a[mt][kc]  = *reinterpret_cast<const bf16x8*>(&As[buf][ra][((((kc << 2) | q4) ^ (ra & 7)) << 3)]);
        const int rb = wn + mt * 16 + fr;
        bb[mt][kc] = *reinterpret_cast<const bf16x8*>(&Bs[buf][rb][((((kc << 2) | q4) ^ (rb & 7)) << 3)]);
      }
    #pragma unroll
    for (int mt = 0; mt < 4; ++mt)
      #pragma unroll
      for (int nt = 0; nt < 4; ++nt) {
        acc[mt][nt] = __builtin_amdgcn_mfma_f32_16x16x32_bf16(a[mt][0], bb[nt][0], acc[mt][nt], 0, 0, 0);
        acc[mt][nt] = __builtin_amdgcn_mfma_f32_16x16x32_bf16(a[mt][1], bb[nt][1], acc[mt][nt], 0, 0, 0);
      }
    __syncthreads();
    buf ^= 1;
  }
  // C/D layout: col = lane&15, row = (lane>>4)*4 + reg (verified m89)
  const int crow0 = bm + wm + (q4 << 2);
  const int ccol0 = bn + wn + fr;
  if (mode == 0) {
    #pragma unroll
    for (int mt = 0; mt < 4; ++mt)
      #pragma unroll
      for (int r = 0; r < 4; ++r) {
        const size_t rr = crow0 + mt * 16 + r;
        #pragma unroll
        for (int nt = 0; nt < 4; ++nt)
          Chi[rr * 1536 + ccol0 + nt * 16] = f2b(acc[mt][nt][r]);
      }
  } else {
    #pragma unroll
    for (int mt = 0; mt < 4; ++mt)
      #pragma unroll
      for (int r = 0; r < 4; ++r) {
        const int rr = crow0 + mt * 16 + r;
        const size_t orow = (size_t)(rr % SQ) * BB + (rr / SQ);
        #pragma unroll
        for (int nt = 0; nt < 4; ++nt)
          Cf[orow * N + ccol0 + nt * 16] = acc[mt][nt][r];
      }
  }
}

// ---------------------------------------------------------------------------
// MFMA attention v9: ONE block per (b,n), 768 thr = 12 waves.
// Rel-shift via diagonal-compacted UD: score (i,j) reads UD[(j+191)%192][i];
//   writer puts U[i][t] at (m=(t+i)%192, col = (t+i>=191 ? i : i-1)), skipping
//   col<0; unwritten diagonal slots UD[m][m] (m<191) zeroed => j==i+1 free.
//   => gather = 12 vector b64 reads, branch-free.
// ASCALE folded into aw/ar (exact pow2). Max-free softmax.
// LDS (shorts): Q[0,12288) R[12288,24576) K[24576,36864) UD/P[36864,75264);
//   VT overlays [0,12800); OH/OL overlay [0,30720) after PV. 5 barriers.
// ---------------------------------------------------------------------------
#define Q0   0
#define R0   12288
#define K0   24576
#define U0   36864
#define VT0  0
#define OH0  0
#define OL0  15360
#define UPIT 200

__global__ __launch_bounds__(768) void attn_mfma(
    const unsigned short* __restrict__ qkvhi,  // [CB*192][1536] chunk-local
    const unsigned short* __restrict__ rhkb,   // [192][512]
    const float* __restrict__ rwb, const float* __restrict__ rrb,
    unsigned short* __restrict__ avhi, unsigned short* __restrict__ avlo, int b0) {
  __shared__ __align__(16) unsigned short lds[75264];   // 150528 B
  const int bid = blockIdx.x;
  const int n = bid & 7, bl = bid >> 3;
  const int tid = threadIdx.x;
  const int lane = tid & 63, wv = tid >> 6;
  const int fr = lane & 15, q4 = lane >> 4;
  const int wrow = (wv / 6) * 96 + (wv % 6) * 16;   // wave's 16-row q-slab
  const int i0q = wrow + (q4 << 2);                 // this lane's 4 q-rows
  const size_t rin = (size_t)bl * SQ;
  const size_t rout = (size_t)(b0 + bl) * SQ;

  // ---- stage: Q, R, K via gload16; V -> regs; zero UD diagonal ----
  #pragma unroll
  for (int it = 0; it < 2; ++it) {
    const int u = it * 768 + tid;
    const int row = u >> 3, sl = u & 7, sp = (sl ^ (row & 7)) << 3;
    gload16(qkvhi + (rin + row) * 1536 + n * 64 + sp, &lds[Q0 + (row << 6) + (sl << 3)]);
    gload16(rhkb + (size_t)row * 512 + n * 64 + sp, &lds[R0 + (row << 6) + (sl << 3)]);
    gload16(qkvhi + (rin + row) * 1536 + 512 + n * 64 + sp, &lds[K0 + (row << 6) + (sl << 3)]);
  }
  if (tid < 191) lds[U0 + tid * UPIT + tid] = 0;   // diag slots (j==i+1 -> 0)
  const int vj = tid % 192, vdg = tid / 192;        // vdg in [0,4)
  u16x8 vreg[2];
  #pragma unroll
  for (int c = 0; c < 2; ++c)
    vreg[c] = *reinterpret_cast<const u16x8*>(qkvhi + (rin + vj) * 1536 + 1024 + n * 64 + vdg * 16 + c * 8);
  __syncthreads();   // barrier A

  // ---- biased+scaled A-frags: aw = bf16((q+rwb)/8), ar = bf16((q+rrb)/8) ----
  bf16x8 aw[2], ar[2];
  {
    const int row_l = wrow + fr;
    #pragma unroll
    for (int kc = 0; kc < 2; ++kc) {
      const u16x8 qraw = *reinterpret_cast<const u16x8*>(
          &lds[Q0 + (row_l << 6) + ((((kc << 2) | q4) ^ (row_l & 7)) << 3)]);
      u16x8 wv_, rv_;
      #pragma unroll
      for (int e = 0; e < 8; ++e) {
        const int k = kc * 32 + (q4 << 3) + e;
        const float qf = b2f(qraw[e]);
        wv_[e] = f2b((qf + rwb[n * 64 + k]) * ASCALE);
        rv_[e] = f2b((qf + rrb[n * 64 + k]) * ASCALE);
      }
      aw[kc] = u2b8(wv_); ar[kc] = u2b8(rv_);
    }
  }

  // ---- AC = (q+rwb).K^T/8 ; U = (q+rrb).R^T/8 ----
  f32x4 acc[12], uacc[12];
  #pragma unroll
  for (int nt = 0; nt < 12; ++nt) {
    acc[nt] = (f32x4){0.f, 0.f, 0.f, 0.f};
    uacc[nt] = (f32x4){0.f, 0.f, 0.f, 0.f};
  }
  #pragma unroll
  for (int nt = 0; nt < 12; ++nt) {
    #pragma unroll
    for (int kc = 0; kc < 2; ++kc) {
      const int r_ = nt * 16 + fr;
      const int sp = ((((kc << 2) | q4) ^ (r_ & 7)) << 3);
      const bf16x8 bk = *reinterpret_cast<const bf16x8*>(&lds[K0 + (r_ << 6) + sp]);
      const bf16x8 br = *reinterpret_cast<const bf16x8*>(&lds[R0 + (r_ << 6) + sp]);
      acc[nt]  = __builtin_amdgcn_mfma_f32_16x16x32_bf16(aw[kc], bk, acc[nt], 0, 0, 0);
      uacc[nt] = __builtin_amdgcn_mfma_f32_16x16x32_bf16(ar[kc], br, uacc[nt], 0, 0, 0);
    }
  }
  // ---- UD scatter: U[i][t] -> (m=(t+i)%192, col= t+i>=191 ? i : i-1) ----
  #pragma unroll
  for (int nt = 0; nt < 12; ++nt) {
    const int t = nt * 16 + fr;
    #pragma unroll
    for (int r = 0; r < 4; ++r) {
      const int i = i0q + r;
      const int s = t + i;
      const int col = (s >= 191) ? i : (i - 1);
      const int m = (s >= 192) ? (s - 192) : s;
      if (col >= 0) lds[U0 + m * UPIT + col] = f2b(uacc[nt][r]);
    }
  }
  __syncthreads();   // barrier B: Q/R/K reads + UD writes done

  // ---- VT write (overlays Q); branch-free gather + max-free softmax ----
  #pragma unroll
  for (int c = 0; c < 2; ++c)
    #pragma unroll
    for (int e = 0; e < 8; ++e)
      lds[VT0 + (vdg * 16 + c * 8 + e) * UPIT + vj] = vreg[c][e];

  float ls[4] = {0.f, 0.f, 0.f, 0.f};
  #pragma unroll
  for (int nt = 0; nt < 12; ++nt) {
    const int j = nt * 16 + fr;
    const int m = (j == 0) ? 191 : (j - 1);
    const u16x4 uv = *reinterpret_cast<const u16x4*>(&lds[U0 + m * UPIT + i0q]);
    #pragma unroll
    for (int r = 0; r < 4; ++r) {
      const float p = __expf(acc[nt][r] + b2f(uv[r]));
      ls[r] += p;
      acc[nt][r] = p;
    }
  }
  float linv[4];
  #pragma unroll
  for (int r = 0; r < 4; ++r) {
    #pragma unroll
    for (int o = 1; o <= 8; o <<= 1) ls[r] += __shfl_xor(ls[r], o);
    linv[r] = __builtin_amdgcn_rcpf(ls[r]);
  }
  __syncthreads();   // barrier C: UD reads done, VT visible

  // ---- P -> UD region (own-wave rows; PV reads only own rows -> no barrier)
  #pragma unroll
  for (int nt = 0; nt < 12; ++nt)
    #pragma unroll
    for (int r = 0; r < 4; ++r)
      lds[U0 + (i0q + r) * UPIT + nt * 16 + fr] = f2b(acc[nt][r]);

  // ---- PV: out[i][d] = sum_j P[i][j] Vt[d][j] ----
  f32x4 o2[4];
  #pragma unroll
  for (int nt = 0; nt < 4; ++nt) o2[nt] = (f32x4){0.f, 0.f, 0.f, 0.f};
  #pragma unroll
  for (int kc = 0; kc < 6; ++kc) {
    const bf16x8 pa = *reinterpret_cast<const bf16x8*>(
        &lds[U0 + (wrow + fr) * UPIT + kc * 32 + (q4 << 3)]);
    #pragma unroll
    for (int nt = 0; nt < 4; ++nt) {
      const bf16x8 vb = *reinterpret_cast<const bf16x8*>(
          &lds[VT0 + (nt * 16 + fr) * UPIT + kc * 32 + (q4 << 3)]);
      o2[nt] = __builtin_amdgcn_mfma_f32_16x16x32_bf16(pa, vb, o2[nt], 0, 0, 0);
    }
  }
  __syncthreads();   // barrier E: VT/P reads done -> OH/OL may overlay

  // ---- normalize, repack in LDS, coalesced 16B stores ----
  #pragma unroll
  for (int nt = 0; nt < 4; ++nt)
    #pragma unroll
    for (int r = 0; r < 4; ++r) {
      const int i_l = i0q + r;
      const int d = nt * 16 + fr;
      const float v = o2[nt][r] * linv[r];
      lds[OH0 + i_l * 80 + d] = f2b(v);
      lds[OL0 + i_l * 80 + d] = f2b(v - f2bf(v));
    }
  __syncthreads();   // barrier F
  #pragma unroll
  for (int it = 0; it < 2; ++it) {
    const int u = it * 768 + tid;
    const int row = u >> 3, sl = u & 7;
    const size_t gbase = (rout + row) * 512 + n * 64 + sl * 8;
    *reinterpret_cast<u16x8*>(avhi + gbase) = *reinterpret_cast<const u16x8*>(&lds[OH0 + row * 80 + sl * 8]);
    *reinterpret_cast<u16x8*>(avlo + gbase) = *reinterpret_cast<const u16x8*>(&lds[OL0 + row * 80 + sl * 8]);
  }
}

// ---------------------------------------------------------------------------
extern "C" void kernel_launch(void* const* d_in, const int* in_sizes, int n_in,
                              void* d_out, int out_size, void* d_ws, size_t ws_size,
                              hipStream_t stream) {
  const float* inp   = (const float*)d_in[0];
  const float* ln1_g = (const float*)d_in[1];
  const float* ln1_b = (const float*)d_in[2];
  const float* ln2_g = (const float*)d_in[3];
  const float* ln2_b = (const float*)d_in[4];
  const float* Wqkv  = (const float*)d_in[5];
  const float* Wr    = (const float*)d_in[6];
  const float* Wo    = (const float*)d_in[7];
  const float* rwb   = (const float*)d_in[8];
  const float* rrb   = (const float*)d_in[9];
  float* out = (float*)d_out;

  const size_t M = (size_t)SQ * BB;   // 36864
  unsigned short* hbhi = (unsigned short*)d_out;  // parked in d_out

  const int cands[3] = {192, 96, 48};
  int CB = 48;
  for (int ci = 0; ci < 3; ++ci) {
    const int c = cands[ci];
    const size_t need = (size_t)c * SQ * 1536 * 2        // qhi chunk
                      + 2 * M * 512 * 2                  // avhi + avlo
                      + 1536 * 512 * 2 + 512 * 512 * 2   // Wqb + Wob
                      + (size_t)BB * DM * 4 + (size_t)BB * DM * 2;  // pe + rhkb
    if (need <= ws_size) { CB = c; break; }
  }

  char* p = (char*)d_ws;
  unsigned short* qhi  = (unsigned short*)p; p += (size_t)CB * SQ * 1536 * 2;
  unsigned short* avhi = (unsigned short*)p; p += M * 512 * 2;
  unsigned short* avlo = (unsigned short*)p; p += M * 512 * 2;
  unsigned short* Wqb  = (unsigned short*)p; p += (size_t)1536 * 512 * 2;
  unsigned short* Wob  = (unsigned short*)p; p += (size_t)512 * 512 * 2;
  float*          pe   = (float*)p;          p += (size_t)BB * DM * 4;
  unsigned short* rhkb = (unsigned short*)p;

  ln2_kernel<<<SQ * BB, 128, 0, stream>>>(inp, ln1_g, ln1_b, ln2_g, ln2_b, hbhi);
  posemb_kernel<<<(BB * DM + 255) / 256, 256, 0, stream>>>(inp, pe);
  rhk_kernel<<<dim3(BB, DM / 256), 256, 0, stream>>>(pe, Wr, rhkb);
  conv2_kernel<<<(786432 + 262144 + 255) / 256, 256, 0, stream>>>(Wqkv, Wo, Wqb, Wob);

  for (int b0 = 0; b0 < BB; b0 += CB) {
    const int Mc = CB * SQ;
    // QKV: hi-only (K=512) — outputs get bf16-rounded anyway.
    gemm_mfma<<<dim3(1536 / 128, Mc / 128), 256, 0, stream>>>(
        hbhi + (size_t)b0 * SQ * DM, hbhi + (size_t)b0 * SQ * DM, Wqb,
        qhi, nullptr, 1536, 0, 8);
    attn_mfma<<<CB * NH, 768, 0, stream>>>(qhi, rhkb, rwb, rrb, avhi, avlo, b0);
  }

  // OUT: split K'=1024 (av-lo feeds compared output directly)
  gemm_mfma<<<dim3(512 / 128, M / 128), 256, 0, stream>>>(
      avhi, avlo, Wob, nullptr, out, 512, 1, 16);
}